// Round 1
// baseline (719.656 us; speedup 1.0000x reference)
//
#include <hip/hip_runtime.h>
#include <hip/hip_bf16.h>
#include <cstdint>
#include <cstddef>

// Problem constants
#define TT 2048
#define DD 2048
#define NHQ 32
#define NHKV 8
#define DHD 64
#define II 5632

typedef short short8 __attribute__((ext_vector_type(8)));
typedef __bf16 bf16x8 __attribute__((ext_vector_type(8)));
typedef float f32x4 __attribute__((ext_vector_type(4)));

__device__ __forceinline__ float b2f(unsigned short u) {
  union { float f; unsigned int i; } v; v.i = ((unsigned int)u) << 16; return v.f;
}
__device__ __forceinline__ unsigned short f2b(float f) {
  union { float f; unsigned int i; } v; v.f = f;
  unsigned int r = v.i + 0x7FFFu + ((v.i >> 16) & 1u);
  return (unsigned short)(r >> 16);
}

// ---------------- transpose fp32 (K x N) -> bf16 (N x K) ----------------
__global__ void transpose_f32_bf16(const float* __restrict__ src,
                                   unsigned short* __restrict__ dst,
                                   int K, int N) {
  __shared__ float tile[32][33];
  const int bn = blockIdx.x * 32;
  const int bk = blockIdx.y * 32;
  const int tx = threadIdx.x, ty = threadIdx.y;
#pragma unroll
  for (int i = 0; i < 32; i += 8)
    tile[ty + i][tx] = src[(size_t)(bk + ty + i) * N + bn + tx];
  __syncthreads();
#pragma unroll
  for (int i = 0; i < 32; i += 8)
    dst[(size_t)(bn + ty + i) * K + bk + tx] = f2b(tile[tx][ty + i]);
}

// ---------------- RMSNorm fp32 -> bf16 (D=2048, 1 block/row) ----------------
__global__ void rmsnorm_kernel(const float* __restrict__ x,
                               const float* __restrict__ w,
                               unsigned short* __restrict__ out) {
  const int row = blockIdx.x;
  const float* xr = x + (size_t)row * DD;
  const int t = threadIdx.x;
  float4 v0 = ((const float4*)xr)[t];
  float4 v1 = ((const float4*)xr)[t + 256];
  float ss = v0.x * v0.x + v0.y * v0.y + v0.z * v0.z + v0.w * v0.w +
             v1.x * v1.x + v1.y * v1.y + v1.z * v1.z + v1.w * v1.w;
#pragma unroll
  for (int off = 32; off >= 1; off >>= 1) ss += __shfl_xor(ss, off);
  __shared__ float sred[4];
  if ((t & 63) == 0) sred[t >> 6] = ss;
  __syncthreads();
  float tot = sred[0] + sred[1] + sred[2] + sred[3];
  float rs = rsqrtf(tot * (1.0f / DD) + 1e-5f);
  float4 w0 = ((const float4*)w)[t];
  float4 w1v = ((const float4*)w)[t + 256];
  unsigned short* orow = out + (size_t)row * DD;
  ushort4 o0, o1;
  o0.x = f2b(v0.x * rs * w0.x); o0.y = f2b(v0.y * rs * w0.y);
  o0.z = f2b(v0.z * rs * w0.z); o0.w = f2b(v0.w * rs * w0.w);
  o1.x = f2b(v1.x * rs * w1v.x); o1.y = f2b(v1.y * rs * w1v.y);
  o1.z = f2b(v1.z * rs * w1v.z); o1.w = f2b(v1.w * rs * w1v.w);
  ((ushort4*)orow)[t] = o0;
  ((ushort4*)orow)[t + 256] = o1;
}

// ---------------- GEMM: C[M,N] = A[M,K] * Bt[N,K]^T (bf16 in, fp32 acc) ------
// EPI 0: C bf16.  EPI 1: C fp32 = acc + resid.
template <int EPI>
__launch_bounds__(256, 2)
__global__ void gemm_bt(const unsigned short* __restrict__ A, int lda,
                        const unsigned short* __restrict__ Bt, int ldb,
                        int K,
                        const float* __restrict__ resid,
                        void* __restrict__ Cout, int ldc) {
  constexpr int BKP = 40;  // padded LDS row stride (shorts); 80B, 16B-aligned
  __shared__ __align__(16) unsigned short As[128 * BKP];
  __shared__ __align__(16) unsigned short Bs[128 * BKP];
  const int bm = blockIdx.y * 128;
  const int bn = blockIdx.x * 128;
  const int tid = threadIdx.x;
  const int lane = tid & 63;
  const int L = lane & 15, G = lane >> 4;
  const int w = tid >> 6;
  const int wr = (w >> 1) * 64, wc = (w & 1) * 64;

  const f32x4 zero = {0.f, 0.f, 0.f, 0.f};
  f32x4 acc[4][4];
#pragma unroll
  for (int m = 0; m < 4; ++m)
#pragma unroll
    for (int n = 0; n < 4; ++n) acc[m][n] = zero;

  const int sr = tid >> 2;             // staging row 0..63
  const int sc = (tid & 3) * 8;        // staging col 0/8/16/24
  const unsigned short* Ab = A + (size_t)(bm + sr) * lda + sc;
  const unsigned short* Bb = Bt + (size_t)(bn + sr) * ldb + sc;

  const int nk = K >> 5;
  for (int kt = 0; kt < nk; ++kt) {
    const int ko = kt * 32;
    short8 ra0 = *(const short8*)(Ab + ko);
    short8 ra1 = *(const short8*)(Ab + (size_t)64 * lda + ko);
    short8 rb0 = *(const short8*)(Bb + ko);
    short8 rb1 = *(const short8*)(Bb + (size_t)64 * ldb + ko);
    __syncthreads();
    *(short8*)&As[sr * BKP + sc] = ra0;
    *(short8*)&As[(sr + 64) * BKP + sc] = ra1;
    *(short8*)&Bs[sr * BKP + sc] = rb0;
    *(short8*)&Bs[(sr + 64) * BKP + sc] = rb1;
    __syncthreads();
    bf16x8 af[4], bf[4];
#pragma unroll
    for (int m = 0; m < 4; ++m)
      af[m] = *reinterpret_cast<const bf16x8*>(&As[(wr + m * 16 + L) * BKP + G * 8]);
#pragma unroll
    for (int n = 0; n < 4; ++n)
      bf[n] = *reinterpret_cast<const bf16x8*>(&Bs[(wc + n * 16 + L) * BKP + G * 8]);
#pragma unroll
    for (int m = 0; m < 4; ++m)
#pragma unroll
      for (int n = 0; n < 4; ++n)
        acc[m][n] = __builtin_amdgcn_mfma_f32_16x16x32_bf16(af[m], bf[n], acc[m][n], 0, 0, 0);
  }

#pragma unroll
  for (int m = 0; m < 4; ++m)
#pragma unroll
    for (int n = 0; n < 4; ++n)
#pragma unroll
      for (int i = 0; i < 4; ++i) {
        const int r = bm + wr + m * 16 + G * 4 + i;
        const int c = bn + wc + n * 16 + L;
        const float val = acc[m][n][i];
        if constexpr (EPI == 0) {
          ((unsigned short*)Cout)[(size_t)r * ldc + c] = f2b(val);
        } else {
          ((float*)Cout)[(size_t)r * ldc + c] = val + resid[(size_t)r * ldc + c];
        }
      }
}

// ---------------- Flash attention, causal GQA -------------------------------
// qkv: (T, 3072) bf16: q cols [0,2048)=h*64+d, k cols [2048,2560), v [2560,3072)
// out: (T, 2048) bf16, out[t][h*64+d]
__launch_bounds__(256, 2)
__global__ void attn_kernel(const unsigned short* __restrict__ qkv,
                            unsigned short* __restrict__ out) {
  const int hq = blockIdx.x;
  const int qb = blockIdx.y;
  const int hkv = hq >> 2;
  const int tid = threadIdx.x, lane = tid & 63, w = tid >> 6;
  const int L = lane & 15, G = lane >> 4;

  __shared__ __align__(16) unsigned short Ks[64 * 72];
  __shared__ __align__(16) unsigned short Vt[64 * 72];
  __shared__ __align__(16) unsigned short Ps[4][16 * 72];

  const int qrow = qb * 64 + w * 16;
  bf16x8 qf[2];
#pragma unroll
  for (int d0 = 0; d0 < 2; ++d0)
    qf[d0] = *reinterpret_cast<const bf16x8*>(
        qkv + (size_t)(qrow + L) * 3072 + hq * 64 + d0 * 32 + G * 8);

  const f32x4 zero = {0.f, 0.f, 0.f, 0.f};
  f32x4 o[4];
#pragma unroll
  for (int n = 0; n < 4; ++n) o[n] = zero;
  float mrow[4], lrow[4];
#pragma unroll
  for (int i = 0; i < 4; ++i) { mrow[i] = -1e30f; lrow[i] = 0.f; }

  const int ntile = qb + 1;
  for (int t = 0; t < ntile; ++t) {
    const int s0 = t * 64;
    __syncthreads();  // protect K/V LDS from previous iteration's readers
#pragma unroll
    for (int i2 = 0; i2 < 2; ++i2) {
      const int c = i2 * 256 + tid;
      const int r = c >> 3, col = (c & 7) * 8;
      bf16x8 k8 = *reinterpret_cast<const bf16x8*>(
          qkv + (size_t)(s0 + r) * 3072 + 2048 + hkv * 64 + col);
      *reinterpret_cast<bf16x8*>(&Ks[r * 72 + col]) = k8;
      short8 v8 = *reinterpret_cast<const short8*>(
          qkv + (size_t)(s0 + r) * 3072 + 2560 + hkv * 64 + col);
#pragma unroll
      for (int j = 0; j < 8; ++j)
        Vt[(col + j) * 72 + r] = (unsigned short)v8[j];
    }
    __syncthreads();

    // S = Q K^T (4 kv sub-tiles of 16)
    f32x4 sacc[4];
#pragma unroll
    for (int nt = 0; nt < 4; ++nt) {
      sacc[nt] = zero;
#pragma unroll
      for (int d0 = 0; d0 < 2; ++d0) {
        bf16x8 kf = *reinterpret_cast<const bf16x8*>(
            &Ks[(nt * 16 + L) * 72 + d0 * 32 + G * 8]);
        sacc[nt] = __builtin_amdgcn_mfma_f32_16x16x32_bf16(qf[d0], kf, sacc[nt], 0, 0, 0);
      }
    }

    // online softmax (rows q = qrow + G*4 + i; cols s = s0 + nt*16 + L)
    float pt[4][4];
#pragma unroll
    for (int i = 0; i < 4; ++i) {
      const int q = qrow + G * 4 + i;
      float mx = mrow[i];
#pragma unroll
      for (int nt = 0; nt < 4; ++nt) {
        float sv = sacc[nt][i] * 0.125f;
        const int s = s0 + nt * 16 + L;
        sv = (s <= q) ? sv : -1e30f;
        pt[i][nt] = sv;
        mx = fmaxf(mx, sv);
      }
#pragma unroll
      for (int off = 1; off < 16; off <<= 1) mx = fmaxf(mx, __shfl_xor(mx, off));
      const float scale_o = __expf(mrow[i] - mx);
      float rsum = 0.f;
#pragma unroll
      for (int nt = 0; nt < 4; ++nt) {
        const float p = __expf(pt[i][nt] - mx);
        pt[i][nt] = p;
        rsum += p;
      }
#pragma unroll
      for (int off = 1; off < 16; off <<= 1) rsum += __shfl_xor(rsum, off);
      mrow[i] = mx;
      lrow[i] = lrow[i] * scale_o + rsum;
#pragma unroll
      for (int nt = 0; nt < 4; ++nt) o[nt][i] *= scale_o;
    }

    // stage P (per-wave) and do PV
#pragma unroll
    for (int i = 0; i < 4; ++i)
#pragma unroll
      for (int nt = 0; nt < 4; ++nt)
        Ps[w][(G * 4 + i) * 72 + nt * 16 + L] = f2b(pt[i][nt]);
#pragma unroll
    for (int kc = 0; kc < 2; ++kc) {
      bf16x8 pf = *reinterpret_cast<const bf16x8*>(&Ps[w][L * 72 + kc * 32 + G * 8]);
#pragma unroll
      for (int nt = 0; nt < 4; ++nt) {
        bf16x8 vf = *reinterpret_cast<const bf16x8*>(
            &Vt[(nt * 16 + L) * 72 + kc * 32 + G * 8]);
        o[nt] = __builtin_amdgcn_mfma_f32_16x16x32_bf16(pf, vf, o[nt], 0, 0, 0);
      }
    }
  }

#pragma unroll
  for (int nt = 0; nt < 4; ++nt)
#pragma unroll
    for (int i = 0; i < 4; ++i) {
      const float val = o[nt][i] / lrow[i];
      out[(size_t)(qrow + G * 4 + i) * 2048 + hq * 64 + nt * 16 + L] = f2b(val);
    }
}

// ---------------- SwiGLU in-place over gate half of fc1 ---------------------
__global__ void swiglu_kernel(unsigned short* __restrict__ fc1) {
  const size_t total = (size_t)TT * (II / 8);  // 2048*704
  const size_t idx = (size_t)blockIdx.x * blockDim.x + threadIdx.x;
  if (idx >= total) return;
  const int m = (int)(idx / (II / 8));
  const int jc = (int)(idx % (II / 8));
  unsigned short* g = fc1 + (size_t)m * (2 * II) + jc * 8;
  short8 gv = *(const short8*)g;
  short8 vv = *(const short8*)(g + II);
  short8 ov;
#pragma unroll
  for (int j = 0; j < 8; ++j) {
    const float gf = b2f((unsigned short)gv[j]);
    const float vf = b2f((unsigned short)vv[j]);
    const float s = gf / (1.f + __expf(-gf));
    ov[j] = (short)f2b(s * vf);
  }
  *(short8*)g = ov;
}

// ---------------- launch ----------------------------------------------------
extern "C" void kernel_launch(void* const* d_in, const int* in_sizes, int n_in,
                              void* d_out, int out_size, void* d_ws, size_t ws_size,
                              hipStream_t stream) {
  const float* x    = (const float*)d_in[0];
  const float* ln1w = (const float*)d_in[1];
  const float* ln2w = (const float*)d_in[2];
  const float* wq   = (const float*)d_in[3];
  const float* wk   = (const float*)d_in[4];
  const float* wv   = (const float*)d_in[5];
  const float* wo   = (const float*)d_in[6];
  const float* w1   = (const float*)d_in[7];
  const float* w2   = (const float*)d_in[8];
  float* outp = (float*)d_out;

  char* ws = (char*)d_ws;
  size_t off = 0;
  auto alloc = [&](size_t bytes) {
    char* p = ws + off;
    off += (bytes + 255) & ~(size_t)255;
    return p;
  };
  unsigned short* wqkvT = (unsigned short*)alloc((size_t)3072 * 2048 * 2);
  unsigned short* woT   = (unsigned short*)alloc((size_t)2048 * 2048 * 2);
  unsigned short* w1T   = (unsigned short*)alloc((size_t)11264 * 2048 * 2);
  unsigned short* w2T   = (unsigned short*)alloc((size_t)2048 * 5632 * 2);
  unsigned short* h     = (unsigned short*)alloc((size_t)2048 * 2048 * 2);
  unsigned short* qkv   = (unsigned short*)alloc((size_t)2048 * 3072 * 2);
  unsigned short* attnb = (unsigned short*)alloc((size_t)2048 * 2048 * 2);
  float*          x2    = (float*)alloc((size_t)2048 * 2048 * 4);
  unsigned short* h2    = (unsigned short*)alloc((size_t)2048 * 2048 * 2);
  unsigned short* fc1   = (unsigned short*)alloc((size_t)2048 * 11264 * 2);
  (void)ws_size; (void)in_sizes; (void)n_in; (void)out_size;

  dim3 tb(32, 8);
  transpose_f32_bf16<<<dim3(2048 / 32, 2048 / 32), tb, 0, stream>>>(wq, wqkvT, 2048, 2048);
  transpose_f32_bf16<<<dim3(512 / 32, 2048 / 32), tb, 0, stream>>>(wk, wqkvT + (size_t)2048 * 2048, 2048, 512);
  transpose_f32_bf16<<<dim3(512 / 32, 2048 / 32), tb, 0, stream>>>(wv, wqkvT + (size_t)2560 * 2048, 2048, 512);
  transpose_f32_bf16<<<dim3(2048 / 32, 2048 / 32), tb, 0, stream>>>(wo, woT, 2048, 2048);
  transpose_f32_bf16<<<dim3(11264 / 32, 2048 / 32), tb, 0, stream>>>(w1, w1T, 2048, 11264);
  transpose_f32_bf16<<<dim3(2048 / 32, 5632 / 32), tb, 0, stream>>>(w2, w2T, 5632, 2048);

  rmsnorm_kernel<<<2048, 256, 0, stream>>>(x, ln1w, h);

  // QKV fused GEMM: (2048 x 3072) = h @ [wq|wk|wv]
  gemm_bt<0><<<dim3(3072 / 128, 2048 / 128), 256, 0, stream>>>(
      h, 2048, wqkvT, 2048, 2048, nullptr, qkv, 3072);

  attn_kernel<<<dim3(NHQ, TT / 64), 256, 0, stream>>>(qkv, attnb);

  // x2 = x + attn @ wo
  gemm_bt<1><<<dim3(2048 / 128, 2048 / 128), 256, 0, stream>>>(
      attnb, 2048, woT, 2048, 2048, x, x2, 2048);

  rmsnorm_kernel<<<2048, 256, 0, stream>>>(x2, ln2w, h2);

  // fc1 = h2 @ w1  (2048 x 11264)
  gemm_bt<0><<<dim3(11264 / 128, 2048 / 128), 256, 0, stream>>>(
      h2, 2048, w1T, 2048, 2048, nullptr, fc1, 11264);

  swiglu_kernel<<<5632, 256, 0, stream>>>(fc1);

  // out = x2 + sw @ w2   (sw lives in gate half of fc1, lda = 11264)
  gemm_bt<1><<<dim3(2048 / 128, 2048 / 128), 256, 0, stream>>>(
      fc1, 11264, w2T, 5632, 5632, x2, outp, 2048);
}

// Round 2
// 679.647 us; speedup vs baseline: 1.0589x; 1.0589x over previous
//
#include <hip/hip_runtime.h>
#include <hip/hip_bf16.h>
#include <cstdint>
#include <cstddef>

// Problem constants
#define TT 2048
#define DD 2048
#define NHQ 32
#define NHKV 8
#define DHD 64
#define II 5632

typedef short short8 __attribute__((ext_vector_type(8)));
typedef __bf16 bf16x8 __attribute__((ext_vector_type(8)));
typedef float f32x4 __attribute__((ext_vector_type(4)));

__device__ __forceinline__ float b2f(unsigned short u) {
  union { float f; unsigned int i; } v; v.i = ((unsigned int)u) << 16; return v.f;
}
__device__ __forceinline__ unsigned short f2b(float f) {
  union { float f; unsigned int i; } v; v.f = f;
  unsigned int r = v.i + 0x7FFFu + ((v.i >> 16) & 1u);
  return (unsigned short)(r >> 16);
}

// global -> LDS direct copy, 16B per lane. lptr is the wave-uniform (lane-0)
// LDS destination; HW adds lane*16. CK-style addrspace cast (low 32 bits of a
// generic LDS pointer are the LDS offset).
__device__ __forceinline__ void gload16(const unsigned short* g, unsigned short* l) {
  __builtin_amdgcn_global_load_lds(
      (const __attribute__((address_space(1))) void*)g,
      (__attribute__((address_space(3))) void*)(unsigned int)(uintptr_t)l,
      16, 0, 0);
}

// ---------------- transpose fp32 (K x N) -> bf16 (N x K) ----------------
__global__ void transpose_f32_bf16(const float* __restrict__ src,
                                   unsigned short* __restrict__ dst,
                                   int K, int N) {
  __shared__ float tile[32][33];
  const int bn = blockIdx.x * 32;
  const int bk = blockIdx.y * 32;
  const int tx = threadIdx.x, ty = threadIdx.y;
#pragma unroll
  for (int i = 0; i < 32; i += 8)
    tile[ty + i][tx] = src[(size_t)(bk + ty + i) * N + bn + tx];
  __syncthreads();
#pragma unroll
  for (int i = 0; i < 32; i += 8)
    dst[(size_t)(bn + ty + i) * K + bk + tx] = f2b(tile[tx][ty + i]);
}

// ---------------- RMSNorm fp32 -> bf16 (D=2048, 1 block/row) ----------------
__global__ void rmsnorm_kernel(const float* __restrict__ x,
                               const float* __restrict__ w,
                               unsigned short* __restrict__ out) {
  const int row = blockIdx.x;
  const float* xr = x + (size_t)row * DD;
  const int t = threadIdx.x;
  float4 v0 = ((const float4*)xr)[t];
  float4 v1 = ((const float4*)xr)[t + 256];
  float ss = v0.x * v0.x + v0.y * v0.y + v0.z * v0.z + v0.w * v0.w +
             v1.x * v1.x + v1.y * v1.y + v1.z * v1.z + v1.w * v1.w;
#pragma unroll
  for (int off = 32; off >= 1; off >>= 1) ss += __shfl_xor(ss, off);
  __shared__ float sred[4];
  if ((t & 63) == 0) sred[t >> 6] = ss;
  __syncthreads();
  float tot = sred[0] + sred[1] + sred[2] + sred[3];
  float rs = rsqrtf(tot * (1.0f / DD) + 1e-5f);
  float4 w0 = ((const float4*)w)[t];
  float4 w1v = ((const float4*)w)[t + 256];
  unsigned short* orow = out + (size_t)row * DD;
  ushort4 o0, o1;
  o0.x = f2b(v0.x * rs * w0.x); o0.y = f2b(v0.y * rs * w0.y);
  o0.z = f2b(v0.z * rs * w0.z); o0.w = f2b(v0.w * rs * w0.w);
  o1.x = f2b(v1.x * rs * w1v.x); o1.y = f2b(v1.y * rs * w1v.y);
  o1.z = f2b(v1.z * rs * w1v.z); o1.w = f2b(v1.w * rs * w1v.w);
  ((ushort4*)orow)[t] = o0;
  ((ushort4*)orow)[t + 256] = o1;
}

// ---------------- GEMM: C[M,N] = A[M,K] * Bt[N,K]^T (bf16 in, fp32 acc) ------
// m97 structure: 128x128 tile, BK=32, global_load_lds width-16 staging,
// linear LDS [128][32], 2 barriers per K-step.
// EPI 0: C bf16.  EPI 1: C fp32 = acc + resid.
template <int EPI>
__global__ void gemm_bt(const unsigned short* __restrict__ A, int lda,
                        const unsigned short* __restrict__ Bt, int ldb,
                        int K,
                        const float* __restrict__ resid,
                        void* __restrict__ Cout, int ldc) {
  __shared__ __align__(16) unsigned short As[128 * 32];
  __shared__ __align__(16) unsigned short Bs[128 * 32];
  const int bm = blockIdx.y * 128;
  const int bn = blockIdx.x * 128;
  const int tid = threadIdx.x;
  const int lane = tid & 63;
  const int L = lane & 15, G = lane >> 4;
  const int w = tid >> 6;
  const int wr = (w >> 1) * 64, wc = (w & 1) * 64;

  const f32x4 zero = {0.f, 0.f, 0.f, 0.f};
  f32x4 acc[4][4];
#pragma unroll
  for (int m = 0; m < 4; ++m)
#pragma unroll
    for (int n = 0; n < 4; ++n) acc[m][n] = zero;

  // staging addresses: wave w covers tile rows [w*32, w*32+32) in two
  // 1024B instructions; lane covers row w*32 + i*16 + (lane>>2), col (lane&3)*8
  const int srow = w * 32 + (lane >> 2);
  const int scol = (lane & 3) * 8;
  const unsigned short* gA = A + (size_t)(bm + srow) * lda + scol;
  const unsigned short* gB = Bt + (size_t)(bn + srow) * ldb + scol;
  unsigned short* lA0 = &As[w * 1024];
  unsigned short* lA1 = &As[w * 1024 + 512];
  unsigned short* lB0 = &Bs[w * 1024];
  unsigned short* lB1 = &Bs[w * 1024 + 512];

  const int nk = K >> 5;
  for (int kt = 0; kt < nk; ++kt) {
    const int ko = kt * 32;
    __syncthreads();  // protect LDS from previous iteration's readers
    gload16(gA + ko, lA0);
    gload16(gA + (size_t)16 * lda + ko, lA1);
    gload16(gB + ko, lB0);
    gload16(gB + (size_t)16 * ldb + ko, lB1);
    __syncthreads();  // (compiler emits vmcnt(0) drain here)
    bf16x8 af[4], bfr[4];
#pragma unroll
    for (int m = 0; m < 4; ++m)
      af[m] = *reinterpret_cast<const bf16x8*>(&As[(wr + m * 16 + L) * 32 + G * 8]);
#pragma unroll
    for (int n = 0; n < 4; ++n)
      bfr[n] = *reinterpret_cast<const bf16x8*>(&Bs[(wc + n * 16 + L) * 32 + G * 8]);
#pragma unroll
    for (int m = 0; m < 4; ++m)
#pragma unroll
      for (int n = 0; n < 4; ++n)
        acc[m][n] = __builtin_amdgcn_mfma_f32_16x16x32_bf16(af[m], bfr[n], acc[m][n], 0, 0, 0);
  }

#pragma unroll
  for (int m = 0; m < 4; ++m)
#pragma unroll
    for (int n = 0; n < 4; ++n)
#pragma unroll
      for (int i = 0; i < 4; ++i) {
        const int r = bm + wr + m * 16 + G * 4 + i;
        const int c = bn + wc + n * 16 + L;
        const float val = acc[m][n][i];
        if constexpr (EPI == 0) {
          ((unsigned short*)Cout)[(size_t)r * ldc + c] = f2b(val);
        } else {
          ((float*)Cout)[(size_t)r * ldc + c] = val + resid[(size_t)r * ldc + c];
        }
      }
}

// ---------------- Flash attention, causal GQA -------------------------------
// qkv: (T, 3072) bf16: q cols [0,2048)=h*64+d, k cols [2048,2560), v [2560,3072)
// out: (T, 2048) bf16, out[t][h*64+d]
// Vt and Ps use an XOR column-swizzle (col ^ ((f(row))<<3) in shorts) to break
// the 16-way (Vt write) / 4-way (Ps write) bank conflicts of the unswizzled
// layout; same bijection applied on the read side, 16B alignment preserved.
__launch_bounds__(256, 2)
__global__ void attn_kernel(const unsigned short* __restrict__ qkv,
                            unsigned short* __restrict__ out) {
  const int hq = blockIdx.x;
  const int qb = blockIdx.y;
  const int hkv = hq >> 2;
  const int tid = threadIdx.x, lane = tid & 63, w = tid >> 6;
  const int L = lane & 15, G = lane >> 4;

  __shared__ __align__(16) unsigned short Ks[64 * 72];
  __shared__ __align__(16) unsigned short Vt[64 * 72];
  __shared__ __align__(16) unsigned short Ps[4][16 * 72];

  const int qrow = qb * 64 + w * 16;
  bf16x8 qf[2];
#pragma unroll
  for (int d0 = 0; d0 < 2; ++d0)
    qf[d0] = *reinterpret_cast<const bf16x8*>(
        qkv + (size_t)(qrow + L) * 3072 + hq * 64 + d0 * 32 + G * 8);

  const f32x4 zero = {0.f, 0.f, 0.f, 0.f};
  f32x4 o[4];
#pragma unroll
  for (int n = 0; n < 4; ++n) o[n] = zero;
  float mrow[4], lrow[4];
#pragma unroll
  for (int i = 0; i < 4; ++i) { mrow[i] = -1e30f; lrow[i] = 0.f; }

  const int ntile = qb + 1;
  for (int t = 0; t < ntile; ++t) {
    const int s0 = t * 64;
    __syncthreads();  // protect K/V LDS from previous iteration's readers
#pragma unroll
    for (int i2 = 0; i2 < 2; ++i2) {
      const int c = i2 * 256 + tid;
      const int r = c >> 3, col = (c & 7) * 8;
      bf16x8 k8 = *reinterpret_cast<const bf16x8*>(
          qkv + (size_t)(s0 + r) * 3072 + 2048 + hkv * 64 + col);
      *reinterpret_cast<bf16x8*>(&Ks[r * 72 + col]) = k8;
      short8 v8 = *reinterpret_cast<const short8*>(
          qkv + (size_t)(s0 + r) * 3072 + 2560 + hkv * 64 + col);
#pragma unroll
      for (int j = 0; j < 8; ++j) {
        const int d = col + j;
        Vt[d * 72 + (r ^ (((d >> 3) & 7) << 3))] = (unsigned short)v8[j];
      }
    }
    __syncthreads();

    // S = Q K^T (4 kv sub-tiles of 16)
    f32x4 sacc[4];
#pragma unroll
    for (int nt = 0; nt < 4; ++nt) {
      sacc[nt] = zero;
#pragma unroll
      for (int d0 = 0; d0 < 2; ++d0) {
        bf16x8 kf = *reinterpret_cast<const bf16x8*>(
            &Ks[(nt * 16 + L) * 72 + d0 * 32 + G * 8]);
        sacc[nt] = __builtin_amdgcn_mfma_f32_16x16x32_bf16(qf[d0], kf, sacc[nt], 0, 0, 0);
      }
    }

    // online softmax (rows q = qrow + G*4 + i; cols s = s0 + nt*16 + L)
    float pt[4][4];
#pragma unroll
    for (int i = 0; i < 4; ++i) {
      const int q = qrow + G * 4 + i;
      float mx = mrow[i];
#pragma unroll
      for (int nt = 0; nt < 4; ++nt) {
        float sv = sacc[nt][i] * 0.125f;
        const int s = s0 + nt * 16 + L;
        sv = (s <= q) ? sv : -1e30f;
        pt[i][nt] = sv;
        mx = fmaxf(mx, sv);
      }
#pragma unroll
      for (int off = 1; off < 16; off <<= 1) mx = fmaxf(mx, __shfl_xor(mx, off));
      const float scale_o = __expf(mrow[i] - mx);
      float rsum = 0.f;
#pragma unroll
      for (int nt = 0; nt < 4; ++nt) {
        const float p = __expf(pt[i][nt] - mx);
        pt[i][nt] = p;
        rsum += p;
      }
#pragma unroll
      for (int off = 1; off < 16; off <<= 1) rsum += __shfl_xor(rsum, off);
      mrow[i] = mx;
      lrow[i] = lrow[i] * scale_o + rsum;
#pragma unroll
      for (int nt = 0; nt < 4; ++nt) o[nt][i] *= scale_o;
    }

    // stage P (per-wave, row-swizzled) and do PV
#pragma unroll
    for (int i = 0; i < 4; ++i) {
      const int prow = G * 4 + i;
#pragma unroll
      for (int nt = 0; nt < 4; ++nt)
        Ps[w][prow * 72 + ((nt * 16 + L) ^ ((prow & 7) << 3))] = f2b(pt[i][nt]);
    }
#pragma unroll
    for (int kc = 0; kc < 2; ++kc) {
      bf16x8 pf = *reinterpret_cast<const bf16x8*>(
          &Ps[w][L * 72 + ((kc * 32 + G * 8) ^ ((L & 7) << 3))]);
#pragma unroll
      for (int nt = 0; nt < 4; ++nt) {
        const int vrow = nt * 16 + L;
        bf16x8 vf = *reinterpret_cast<const bf16x8*>(
            &Vt[vrow * 72 + ((kc * 32 + G * 8) ^ (((vrow >> 3) & 7) << 3))]);
        o[nt] = __builtin_amdgcn_mfma_f32_16x16x32_bf16(pf, vf, o[nt], 0, 0, 0);
      }
    }
  }

#pragma unroll
  for (int nt = 0; nt < 4; ++nt)
#pragma unroll
    for (int i = 0; i < 4; ++i) {
      const float val = o[nt][i] / lrow[i];
      out[(size_t)(qrow + G * 4 + i) * 2048 + hq * 64 + nt * 16 + L] = f2b(val);
    }
}

// ---------------- SwiGLU in-place over gate half of fc1 ---------------------
__global__ void swiglu_kernel(unsigned short* __restrict__ fc1) {
  const size_t total = (size_t)TT * (II / 8);  // 2048*704
  const size_t idx = (size_t)blockIdx.x * blockDim.x + threadIdx.x;
  if (idx >= total) return;
  const int m = (int)(idx / (II / 8));
  const int jc = (int)(idx % (II / 8));
  unsigned short* g = fc1 + (size_t)m * (2 * II) + jc * 8;
  short8 gv = *(const short8*)g;
  short8 vv = *(const short8*)(g + II);
  short8 ov;
#pragma unroll
  for (int j = 0; j < 8; ++j) {
    const float gf = b2f((unsigned short)gv[j]);
    const float vf = b2f((unsigned short)vv[j]);
    const float s = gf / (1.f + __expf(-gf));
    ov[j] = (short)f2b(s * vf);
  }
  *(short8*)g = ov;
}

// ---------------- launch ----------------------------------------------------
extern "C" void kernel_launch(void* const* d_in, const int* in_sizes, int n_in,
                              void* d_out, int out_size, void* d_ws, size_t ws_size,
                              hipStream_t stream) {
  const float* x    = (const float*)d_in[0];
  const float* ln1w = (const float*)d_in[1];
  const float* ln2w = (const float*)d_in[2];
  const float* wq   = (const float*)d_in[3];
  const float* wk   = (const float*)d_in[4];
  const float* wv   = (const float*)d_in[5];
  const float* wo   = (const float*)d_in[6];
  const float* w1   = (const float*)d_in[7];
  const float* w2   = (const float*)d_in[8];
  float* outp = (float*)d_out;

  char* ws = (char*)d_ws;
  size_t off = 0;
  auto alloc = [&](size_t bytes) {
    char* p = ws + off;
    off += (bytes + 255) & ~(size_t)255;
    return p;
  };
  unsigned short* wqkvT = (unsigned short*)alloc((size_t)3072 * 2048 * 2);
  unsigned short* woT   = (unsigned short*)alloc((size_t)2048 * 2048 * 2);
  unsigned short* w1T   = (unsigned short*)alloc((size_t)11264 * 2048 * 2);
  unsigned short* w2T   = (unsigned short*)alloc((size_t)2048 * 5632 * 2);
  unsigned short* h     = (unsigned short*)alloc((size_t)2048 * 2048 * 2);
  unsigned short* qkv   = (unsigned short*)alloc((size_t)2048 * 3072 * 2);
  unsigned short* attnb = (unsigned short*)alloc((size_t)2048 * 2048 * 2);
  float*          x2    = (float*)alloc((size_t)2048 * 2048 * 4);
  unsigned short* h2    = (unsigned short*)alloc((size_t)2048 * 2048 * 2);
  unsigned short* fc1   = (unsigned short*)alloc((size_t)2048 * 11264 * 2);
  (void)ws_size; (void)in_sizes; (void)n_in; (void)out_size;

  dim3 tb(32, 8);
  transpose_f32_bf16<<<dim3(2048 / 32, 2048 / 32), tb, 0, stream>>>(wq, wqkvT, 2048, 2048);
  transpose_f32_bf16<<<dim3(512 / 32, 2048 / 32), tb, 0, stream>>>(wk, wqkvT + (size_t)2048 * 2048, 2048, 512);
  transpose_f32_bf16<<<dim3(512 / 32, 2048 / 32), tb, 0, stream>>>(wv, wqkvT + (size_t)2560 * 2048, 2048, 512);
  transpose_f32_bf16<<<dim3(2048 / 32, 2048 / 32), tb, 0, stream>>>(wo, woT, 2048, 2048);
  transpose_f32_bf16<<<dim3(11264 / 32, 2048 / 32), tb, 0, stream>>>(w1, w1T, 2048, 11264);
  transpose_f32_bf16<<<dim3(2048 / 32, 5632 / 32), tb, 0, stream>>>(w2, w2T, 5632, 2048);

  rmsnorm_kernel<<<2048, 256, 0, stream>>>(x, ln1w, h);

  // QKV fused GEMM: (2048 x 3072) = h @ [wq|wk|wv]
  gemm_bt<0><<<dim3(3072 / 128, 2048 / 128), 256, 0, stream>>>(
      h, 2048, wqkvT, 2048, 2048, nullptr, qkv, 3072);

  attn_kernel<<<dim3(NHQ, TT / 64), 256, 0, stream>>>(qkv, attnb);

  // x2 = x + attn @ wo
  gemm_bt<1><<<dim3(2048 / 128, 2048 / 128), 256, 0, stream>>>(
      attnb, 2048, woT, 2048, 2048, x, x2, 2048);

  rmsnorm_kernel<<<2048, 256, 0, stream>>>(x2, ln2w, h2);

  // fc1 = h2 @ w1  (2048 x 11264)
  gemm_bt<0><<<dim3(11264 / 128, 2048 / 128), 256, 0, stream>>>(
      h2, 2048, w1T, 2048, 2048, nullptr, fc1, 11264);

  swiglu_kernel<<<5632, 256, 0, stream>>>(fc1);

  // out = x2 + sw @ w2   (sw lives in gate half of fc1, lda = 11264)
  gemm_bt<1><<<dim3(2048 / 128, 2048 / 128), 256, 0, stream>>>(
      fc1, 11264, w2T, 5632, 5632, x2, outp, 2048);
}

// Round 3
// 670.020 us; speedup vs baseline: 1.0741x; 1.0144x over previous
//
#include <hip/hip_runtime.h>
#include <hip/hip_bf16.h>
#include <cstdint>
#include <cstddef>

// Problem constants
#define TT 2048
#define DD 2048
#define NHQ 32
#define NHKV 8
#define DHD 64
#define II 5632

typedef short short8 __attribute__((ext_vector_type(8)));
typedef __bf16 bf16x8 __attribute__((ext_vector_type(8)));
typedef float f32x4 __attribute__((ext_vector_type(4)));

__device__ __forceinline__ float b2f(unsigned short u) {
  union { float f; unsigned int i; } v; v.i = ((unsigned int)u) << 16; return v.f;
}
__device__ __forceinline__ unsigned short f2b(float f) {
  union { float f; unsigned int i; } v; v.f = f;
  unsigned int r = v.i + 0x7FFFu + ((v.i >> 16) & 1u);
  return (unsigned short)(r >> 16);
}

// global -> LDS direct copy, 16B per lane. l is the wave-uniform (lane-0)
// LDS destination; HW adds lane*16.
__device__ __forceinline__ void gload16(const unsigned short* g, unsigned short* l) {
  __builtin_amdgcn_global_load_lds(
      (const __attribute__((address_space(1))) void*)g,
      (__attribute__((address_space(3))) void*)(unsigned int)(uintptr_t)l,
      16, 0, 0);
}

#define WAITVM(N) asm volatile("s_waitcnt vmcnt(" #N ")" ::: "memory")
#define BARRIER() do { asm volatile("" ::: "memory"); __builtin_amdgcn_s_barrier(); \
                       asm volatile("" ::: "memory"); } while (0)

// ---------------- transpose fp32 (K x N) -> bf16 (N x K), 64x64 tiles -------
__global__ void transpose_f32_bf16(const float* __restrict__ src,
                                   unsigned short* __restrict__ dst,
                                   int K, int N) {
  __shared__ unsigned short tile[64][70];  // pad 70: write-gather is 2-way max
  const int bn = blockIdx.x * 64;
  const int bk = blockIdx.y * 64;
  const int tid = threadIdx.x;           // 256
  const int rr = tid >> 4, c4 = (tid & 15) * 4;
#pragma unroll
  for (int j = 0; j < 4; ++j) {
    const int r = rr + j * 16;
    float4 v = *(const float4*)(src + (size_t)(bk + r) * N + bn + c4);
    ushort4 u;
    u.x = f2b(v.x); u.y = f2b(v.y); u.z = f2b(v.z); u.w = f2b(v.w);
    *(ushort4*)&tile[r][c4] = u;
  }
  __syncthreads();
#pragma unroll
  for (int j = 0; j < 4; ++j) {
    const int n = rr + j * 16;  // output row (= src col)
    ushort4 u;
    u.x = tile[c4 + 0][n];
    u.y = tile[c4 + 1][n];
    u.z = tile[c4 + 2][n];
    u.w = tile[c4 + 3][n];
    *(ushort4*)(dst + (size_t)(bn + n) * K + bk + c4) = u;
  }
}

// ---------------- RMSNorm fp32 -> bf16 (D=2048, 1 block/row) ----------------
__global__ void rmsnorm_kernel(const float* __restrict__ x,
                               const float* __restrict__ w,
                               unsigned short* __restrict__ out) {
  const int row = blockIdx.x;
  const float* xr = x + (size_t)row * DD;
  const int t = threadIdx.x;
  float4 v0 = ((const float4*)xr)[t];
  float4 v1 = ((const float4*)xr)[t + 256];
  float ss = v0.x * v0.x + v0.y * v0.y + v0.z * v0.z + v0.w * v0.w +
             v1.x * v1.x + v1.y * v1.y + v1.z * v1.z + v1.w * v1.w;
#pragma unroll
  for (int off = 32; off >= 1; off >>= 1) ss += __shfl_xor(ss, off);
  __shared__ float sred[4];
  if ((t & 63) == 0) sred[t >> 6] = ss;
  __syncthreads();
  float tot = sred[0] + sred[1] + sred[2] + sred[3];
  float rs = rsqrtf(tot * (1.0f / DD) + 1e-5f);
  float4 w0 = ((const float4*)w)[t];
  float4 w1v = ((const float4*)w)[t + 256];
  unsigned short* orow = out + (size_t)row * DD;
  ushort4 o0, o1;
  o0.x = f2b(v0.x * rs * w0.x); o0.y = f2b(v0.y * rs * w0.y);
  o0.z = f2b(v0.z * rs * w0.z); o0.w = f2b(v0.w * rs * w0.w);
  o1.x = f2b(v1.x * rs * w1v.x); o1.y = f2b(v1.y * rs * w1v.y);
  o1.z = f2b(v1.z * rs * w1v.z); o1.w = f2b(v1.w * rs * w1v.w);
  ((ushort4*)orow)[t] = o0;
  ((ushort4*)orow)[t + 256] = o1;
}

// ---------------- GEMM (m97-style 128x128): C = A * Bt^T --------------------
// EPI 0: C bf16.  EPI 1: C fp32 = acc + resid.
template <int EPI>
__global__ void gemm_bt(const unsigned short* __restrict__ A, int lda,
                        const unsigned short* __restrict__ Bt, int ldb,
                        int K,
                        const float* __restrict__ resid,
                        void* __restrict__ Cout, int ldc) {
  __shared__ __align__(16) unsigned short As[128 * 32];
  __shared__ __align__(16) unsigned short Bs[128 * 32];
  const int bm = blockIdx.y * 128;
  const int bn = blockIdx.x * 128;
  const int tid = threadIdx.x;
  const int lane = tid & 63;
  const int L = lane & 15, G = lane >> 4;
  const int w = tid >> 6;
  const int wr = (w >> 1) * 64, wc = (w & 1) * 64;

  const f32x4 zero = {0.f, 0.f, 0.f, 0.f};
  f32x4 acc[4][4];
#pragma unroll
  for (int m = 0; m < 4; ++m)
#pragma unroll
    for (int n = 0; n < 4; ++n) acc[m][n] = zero;

  const int srow = w * 32 + (lane >> 2);
  const int scol = (lane & 3) * 8;
  const unsigned short* gA = A + (size_t)(bm + srow) * lda + scol;
  const unsigned short* gB = Bt + (size_t)(bn + srow) * ldb + scol;
  unsigned short* lA0 = &As[w * 1024];
  unsigned short* lA1 = &As[w * 1024 + 512];
  unsigned short* lB0 = &Bs[w * 1024];
  unsigned short* lB1 = &Bs[w * 1024 + 512];

  const int nk = K >> 5;
  for (int kt = 0; kt < nk; ++kt) {
    const int ko = kt * 32;
    __syncthreads();
    gload16(gA + ko, lA0);
    gload16(gA + (size_t)16 * lda + ko, lA1);
    gload16(gB + ko, lB0);
    gload16(gB + (size_t)16 * ldb + ko, lB1);
    __syncthreads();
    bf16x8 af[4], bfr[4];
#pragma unroll
    for (int m = 0; m < 4; ++m)
      af[m] = *reinterpret_cast<const bf16x8*>(&As[(wr + m * 16 + L) * 32 + G * 8]);
#pragma unroll
    for (int n = 0; n < 4; ++n)
      bfr[n] = *reinterpret_cast<const bf16x8*>(&Bs[(wc + n * 16 + L) * 32 + G * 8]);
#pragma unroll
    for (int m = 0; m < 4; ++m)
#pragma unroll
      for (int n = 0; n < 4; ++n)
        acc[m][n] = __builtin_amdgcn_mfma_f32_16x16x32_bf16(af[m], bfr[n], acc[m][n], 0, 0, 0);
  }

#pragma unroll
  for (int m = 0; m < 4; ++m)
#pragma unroll
    for (int n = 0; n < 4; ++n)
#pragma unroll
      for (int i = 0; i < 4; ++i) {
        const int r = bm + wr + m * 16 + G * 4 + i;
        const int c = bn + wc + n * 16 + L;
        const float val = acc[m][n][i];
        if constexpr (EPI == 0) {
          ((unsigned short*)Cout)[(size_t)r * ldc + c] = f2b(val);
        } else {
          ((float*)Cout)[(size_t)r * ldc + c] = val + resid[(size_t)r * ldc + c];
        }
      }
}

// ---------------- Wide pipelined GEMM: 128x256 tile, 8 waves, BK=32 ---------
// 4 LDS buffers (96KB), depth-2 counted-vmcnt prefetch, ONE barrier per
// K-step, loads never drained to 0 in the main loop (T3/T4 pattern).
// Race-freedom: stage target (t+2)%4; concurrent-window distances {2,3} mod 4
// are nonzero, so no wave can write a buffer another wave still reads.
// vmcnt(6) leaves exactly tiles {t+1,t+2} (3 loads each) in flight -> tile t
// landed before its barrier. Tail peeled with vmcnt(3)/vmcnt(0).
template <int EPI>
__launch_bounds__(512, 2)
__global__ void gemm_bt_wide(const unsigned short* __restrict__ A, int lda,
                             const unsigned short* __restrict__ Bt, int ldb,
                             int K,
                             const float* __restrict__ resid,
                             void* __restrict__ Cout, int ldc) {
  __shared__ __align__(16) unsigned short As[4][128 * 32];
  __shared__ __align__(16) unsigned short Bs[4][256 * 32];
  const int bm = blockIdx.y * 128;
  const int bn = blockIdx.x * 256;
  const int tid = threadIdx.x;
  const int lane = tid & 63;
  const int L = lane & 15, G = lane >> 4;
  const int w = tid >> 6;           // 0..7
  const int wr = (w >> 2) * 64;     // M offset: 0 / 64
  const int wc = (w & 3) * 64;      // N offset: 0/64/128/192

  const f32x4 zero = {0.f, 0.f, 0.f, 0.f};
  f32x4 acc[4][4];
#pragma unroll
  for (int m = 0; m < 4; ++m)
#pragma unroll
    for (int n = 0; n < 4; ++n) acc[m][n] = zero;

  // staging: 3 x gload16 per thread per K-step (A: 8KB, B: 16KB)
  const int arow = tid >> 2;
  const int slot = (tid & 3) * 8;
  const unsigned short* gA = A + (size_t)(bm + arow) * lda + slot;
  const unsigned short* gB0 = Bt + (size_t)(bn + arow) * ldb + slot;          // rows 0..127
  const unsigned short* gB1 = Bt + (size_t)(bn + 128 + arow) * ldb + slot;    // rows 128..255
  const int ldsA = w * 512;               // shorts, lane-0 base
  const int ldsB0 = w * 512;
  const int ldsB1 = 4096 + w * 512;

  const int nk = K >> 5;  // requires nk >= 3

  // prologue: stage tiles 0,1
  gload16(gA, &As[0][ldsA]);
  gload16(gB0, &Bs[0][ldsB0]);
  gload16(gB1, &Bs[0][ldsB1]);
  gload16(gA + 32, &As[1][ldsA]);
  gload16(gB0 + 32, &Bs[1][ldsB0]);
  gload16(gB1 + 32, &Bs[1][ldsB1]);

  int cb = 0;      // compute buffer = t % 4
  int ko = 64;     // k-offset of tile t+2

  auto COMPUTE = [&](int b) {
    bf16x8 af[4], bfr[4];
#pragma unroll
    for (int m = 0; m < 4; ++m)
      af[m] = *reinterpret_cast<const bf16x8*>(&As[b][(wr + m * 16 + L) * 32 + G * 8]);
#pragma unroll
    for (int n = 0; n < 4; ++n)
      bfr[n] = *reinterpret_cast<const bf16x8*>(&Bs[b][(wc + n * 16 + L) * 32 + G * 8]);
    __builtin_amdgcn_s_setprio(1);
#pragma unroll
    for (int m = 0; m < 4; ++m)
#pragma unroll
      for (int n = 0; n < 4; ++n)
        acc[m][n] = __builtin_amdgcn_mfma_f32_16x16x32_bf16(af[m], bfr[n], acc[m][n], 0, 0, 0);
    __builtin_amdgcn_s_setprio(0);
  };

  for (int t = 0; t < nk - 2; ++t) {
    const int sb = (cb + 2) & 3;
    gload16(gA + ko, &As[sb][ldsA]);
    gload16(gB0 + ko, &Bs[sb][ldsB0]);
    gload16(gB1 + ko, &Bs[sb][ldsB1]);
    ko += 32;
    WAITVM(6);
    BARRIER();
    COMPUTE(cb);
    cb = (cb + 1) & 3;
  }
  // t = nk-2
  WAITVM(3);
  BARRIER();
  COMPUTE(cb);
  cb = (cb + 1) & 3;
  // t = nk-1
  WAITVM(0);
  BARRIER();
  COMPUTE(cb);

#pragma unroll
  for (int m = 0; m < 4; ++m)
#pragma unroll
    for (int n = 0; n < 4; ++n)
#pragma unroll
      for (int i = 0; i < 4; ++i) {
        const int r = bm + wr + m * 16 + G * 4 + i;
        const int c = bn + wc + n * 16 + L;
        const float val = acc[m][n][i];
        if constexpr (EPI == 0) {
          ((unsigned short*)Cout)[(size_t)r * ldc + c] = f2b(val);
        } else {
          ((float*)Cout)[(size_t)r * ldc + c] = val + resid[(size_t)r * ldc + c];
        }
      }
}

// ---------------- Flash attention, causal GQA -------------------------------
__launch_bounds__(256, 2)
__global__ void attn_kernel(const unsigned short* __restrict__ qkv,
                            unsigned short* __restrict__ out) {
  const int hq = blockIdx.x;
  const int qb = blockIdx.y;
  const int hkv = hq >> 2;
  const int tid = threadIdx.x, lane = tid & 63, w = tid >> 6;
  const int L = lane & 15, G = lane >> 4;

  __shared__ __align__(16) unsigned short Ks[64 * 72];
  __shared__ __align__(16) unsigned short Vt[64 * 72];
  __shared__ __align__(16) unsigned short Ps[4][16 * 72];

  const int qrow = qb * 64 + w * 16;
  bf16x8 qf[2];
#pragma unroll
  for (int d0 = 0; d0 < 2; ++d0)
    qf[d0] = *reinterpret_cast<const bf16x8*>(
        qkv + (size_t)(qrow + L) * 3072 + hq * 64 + d0 * 32 + G * 8);

  const f32x4 zero = {0.f, 0.f, 0.f, 0.f};
  f32x4 o[4];
#pragma unroll
  for (int n = 0; n < 4; ++n) o[n] = zero;
  float mrow[4], lrow[4];
#pragma unroll
  for (int i = 0; i < 4; ++i) { mrow[i] = -1e30f; lrow[i] = 0.f; }

  const int ntile = qb + 1;
  for (int t = 0; t < ntile; ++t) {
    const int s0 = t * 64;
    __syncthreads();
#pragma unroll
    for (int i2 = 0; i2 < 2; ++i2) {
      const int c = i2 * 256 + tid;
      const int r = c >> 3, col = (c & 7) * 8;
      bf16x8 k8 = *reinterpret_cast<const bf16x8*>(
          qkv + (size_t)(s0 + r) * 3072 + 2048 + hkv * 64 + col);
      *reinterpret_cast<bf16x8*>(&Ks[r * 72 + col]) = k8;
      short8 v8 = *reinterpret_cast<const short8*>(
          qkv + (size_t)(s0 + r) * 3072 + 2560 + hkv * 64 + col);
#pragma unroll
      for (int j = 0; j < 8; ++j) {
        const int d = col + j;
        Vt[d * 72 + (r ^ (((d >> 3) & 7) << 3))] = (unsigned short)v8[j];
      }
    }
    __syncthreads();

    f32x4 sacc[4];
#pragma unroll
    for (int nt = 0; nt < 4; ++nt) {
      sacc[nt] = zero;
#pragma unroll
      for (int d0 = 0; d0 < 2; ++d0) {
        bf16x8 kf = *reinterpret_cast<const bf16x8*>(
            &Ks[(nt * 16 + L) * 72 + d0 * 32 + G * 8]);
        sacc[nt] = __builtin_amdgcn_mfma_f32_16x16x32_bf16(qf[d0], kf, sacc[nt], 0, 0, 0);
      }
    }

    const bool diag = (t == qb);  // interior tiles need no causal mask
    float pt[4][4];
#pragma unroll
    for (int i = 0; i < 4; ++i) {
      const int q = qrow + G * 4 + i;
      float mx = mrow[i];
#pragma unroll
      for (int nt = 0; nt < 4; ++nt) {
        float sv = sacc[nt][i] * 0.125f;
        if (diag) {
          const int s = s0 + nt * 16 + L;
          sv = (s <= q) ? sv : -1e30f;
        }
        pt[i][nt] = sv;
        mx = fmaxf(mx, sv);
      }
#pragma unroll
      for (int off = 1; off < 16; off <<= 1) mx = fmaxf(mx, __shfl_xor(mx, off));
      const float scale_o = __expf(mrow[i] - mx);
      float rsum = 0.f;
#pragma unroll
      for (int nt = 0; nt < 4; ++nt) {
        const float p = __expf(pt[i][nt] - mx);
        pt[i][nt] = p;
        rsum += p;
      }
#pragma unroll
      for (int off = 1; off < 16; off <<= 1) rsum += __shfl_xor(rsum, off);
      mrow[i] = mx;
      lrow[i] = lrow[i] * scale_o + rsum;
#pragma unroll
      for (int nt = 0; nt < 4; ++nt) o[nt][i] *= scale_o;
    }

#pragma unroll
    for (int i = 0; i < 4; ++i) {
      const int prow = G * 4 + i;
#pragma unroll
      for (int nt = 0; nt < 4; ++nt)
        Ps[w][prow * 72 + ((nt * 16 + L) ^ ((prow & 7) << 3))] = f2b(pt[i][nt]);
    }
#pragma unroll
    for (int kc = 0; kc < 2; ++kc) {
      bf16x8 pf = *reinterpret_cast<const bf16x8*>(
          &Ps[w][L * 72 + ((kc * 32 + G * 8) ^ ((L & 7) << 3))]);
#pragma unroll
      for (int nt = 0; nt < 4; ++nt) {
        const int vrow = nt * 16 + L;
        bf16x8 vf = *reinterpret_cast<const bf16x8*>(
            &Vt[vrow * 72 + ((kc * 32 + G * 8) ^ (((vrow >> 3) & 7) << 3))]);
        o[nt] = __builtin_amdgcn_mfma_f32_16x16x32_bf16(pf, vf, o[nt], 0, 0, 0);
      }
    }
  }

#pragma unroll
  for (int nt = 0; nt < 4; ++nt)
#pragma unroll
    for (int i = 0; i < 4; ++i) {
      const float val = o[nt][i] / lrow[i];
      out[(size_t)(qrow + G * 4 + i) * 2048 + hq * 64 + nt * 16 + L] = f2b(val);
    }
}

// ---------------- SwiGLU in-place over gate half of fc1 ---------------------
__global__ void swiglu_kernel(unsigned short* __restrict__ fc1) {
  const size_t total = (size_t)TT * (II / 8);
  const size_t idx = (size_t)blockIdx.x * blockDim.x + threadIdx.x;
  if (idx >= total) return;
  const int m = (int)(idx / (II / 8));
  const int jc = (int)(idx % (II / 8));
  unsigned short* g = fc1 + (size_t)m * (2 * II) + jc * 8;
  short8 gv = *(const short8*)g;
  short8 vv = *(const short8*)(g + II);
  short8 ov;
#pragma unroll
  for (int j = 0; j < 8; ++j) {
    const float gf = b2f((unsigned short)gv[j]);
    const float vf = b2f((unsigned short)vv[j]);
    const float s = gf / (1.f + __expf(-gf));
    ov[j] = (short)f2b(s * vf);
  }
  *(short8*)g = ov;
}

// ---------------- launch ----------------------------------------------------
extern "C" void kernel_launch(void* const* d_in, const int* in_sizes, int n_in,
                              void* d_out, int out_size, void* d_ws, size_t ws_size,
                              hipStream_t stream) {
  const float* x    = (const float*)d_in[0];
  const float* ln1w = (const float*)d_in[1];
  const float* ln2w = (const float*)d_in[2];
  const float* wq   = (const float*)d_in[3];
  const float* wk   = (const float*)d_in[4];
  const float* wv   = (const float*)d_in[5];
  const float* wo   = (const float*)d_in[6];
  const float* w1   = (const float*)d_in[7];
  const float* w2   = (const float*)d_in[8];
  float* outp = (float*)d_out;

  char* ws = (char*)d_ws;
  size_t off = 0;
  auto alloc = [&](size_t bytes) {
    char* p = ws + off;
    off += (bytes + 255) & ~(size_t)255;
    return p;
  };
  unsigned short* wqkvT = (unsigned short*)alloc((size_t)3072 * 2048 * 2);
  unsigned short* woT   = (unsigned short*)alloc((size_t)2048 * 2048 * 2);
  unsigned short* w1T   = (unsigned short*)alloc((size_t)11264 * 2048 * 2);
  unsigned short* w2T   = (unsigned short*)alloc((size_t)2048 * 5632 * 2);
  unsigned short* h     = (unsigned short*)alloc((size_t)2048 * 2048 * 2);
  unsigned short* qkv   = (unsigned short*)alloc((size_t)2048 * 3072 * 2);
  unsigned short* attnb = (unsigned short*)alloc((size_t)2048 * 2048 * 2);
  float*          x2    = (float*)alloc((size_t)2048 * 2048 * 4);
  unsigned short* h2    = (unsigned short*)alloc((size_t)2048 * 2048 * 2);
  unsigned short* fc1   = (unsigned short*)alloc((size_t)2048 * 11264 * 2);
  (void)ws_size; (void)in_sizes; (void)n_in; (void)out_size;

  transpose_f32_bf16<<<dim3(2048 / 64, 2048 / 64), 256, 0, stream>>>(wq, wqkvT, 2048, 2048);
  transpose_f32_bf16<<<dim3(512 / 64, 2048 / 64), 256, 0, stream>>>(wk, wqkvT + (size_t)2048 * 2048, 2048, 512);
  transpose_f32_bf16<<<dim3(512 / 64, 2048 / 64), 256, 0, stream>>>(wv, wqkvT + (size_t)2560 * 2048, 2048, 512);
  transpose_f32_bf16<<<dim3(2048 / 64, 2048 / 64), 256, 0, stream>>>(wo, woT, 2048, 2048);
  transpose_f32_bf16<<<dim3(11264 / 64, 2048 / 64), 256, 0, stream>>>(w1, w1T, 2048, 11264);
  transpose_f32_bf16<<<dim3(2048 / 64, 5632 / 64), 256, 0, stream>>>(w2, w2T, 5632, 2048);

  rmsnorm_kernel<<<2048, 256, 0, stream>>>(x, ln1w, h);

  // QKV fused GEMM: (2048 x 3072) = h @ [wq|wk|wv]
  gemm_bt<0><<<dim3(3072 / 128, 2048 / 128), 256, 0, stream>>>(
      h, 2048, wqkvT, 2048, 2048, nullptr, qkv, 3072);

  attn_kernel<<<dim3(NHQ, TT / 64), 256, 0, stream>>>(qkv, attnb);

  // x2 = x + attn @ wo
  gemm_bt<1><<<dim3(2048 / 128, 2048 / 128), 256, 0, stream>>>(
      attnb, 2048, woT, 2048, 2048, x, x2, 2048);

  rmsnorm_kernel<<<2048, 256, 0, stream>>>(x2, ln2w, h2);

  // fc1 = h2 @ w1  (2048 x 11264) — wide pipelined kernel
  gemm_bt_wide<0><<<dim3(11264 / 256, 2048 / 128), 512, 0, stream>>>(
      h2, 2048, w1T, 2048, 2048, nullptr, fc1, 11264);

  swiglu_kernel<<<5632, 256, 0, stream>>>(fc1);

  // out = x2 + sw @ w2   (sw lives in gate half of fc1, lda = 11264)
  gemm_bt<1><<<dim3(2048 / 128, 2048 / 128), 256, 0, stream>>>(
      fc1, 11264, w2T, 5632, 5632, x2, outp, 2048);
}

// Round 4
// 614.267 us; speedup vs baseline: 1.1716x; 1.0908x over previous
//
#include <hip/hip_runtime.h>
#include <hip/hip_bf16.h>
#include <cstdint>
#include <cstddef>

// Problem constants
#define TT 2048
#define DD 2048
#define NHQ 32
#define NHKV 8
#define DHD 64
#define II 5632

typedef short short8 __attribute__((ext_vector_type(8)));
typedef __bf16 bf16x8 __attribute__((ext_vector_type(8)));
typedef float f32x4 __attribute__((ext_vector_type(4)));

__device__ __forceinline__ float b2f(unsigned short u) {
  union { float f; unsigned int i; } v; v.i = ((unsigned int)u) << 16; return v.f;
}
__device__ __forceinline__ unsigned short f2b(float f) {
  union { float f; unsigned int i; } v; v.f = f;
  unsigned int r = v.i + 0x7FFFu + ((v.i >> 16) & 1u);
  return (unsigned short)(r >> 16);
}

// global -> LDS direct copy, 16B per lane. l is the wave-uniform (lane-0)
// LDS destination; HW adds lane*16.
__device__ __forceinline__ void gload16(const unsigned short* g, unsigned short* l) {
  __builtin_amdgcn_global_load_lds(
      (const __attribute__((address_space(1))) void*)g,
      (__attribute__((address_space(3))) void*)(unsigned int)(uintptr_t)l,
      16, 0, 0);
}

#define WAITVM(N) asm volatile("s_waitcnt vmcnt(" #N ")" ::: "memory")
#define BARRIER() do { asm volatile("" ::: "memory"); __builtin_amdgcn_s_barrier(); \
                       asm volatile("" ::: "memory"); } while (0)

// ---------------- transpose fp32 (K x N) -> bf16 (N x K), 64x64 tiles -------
__global__ void transpose_f32_bf16(const float* __restrict__ src,
                                   unsigned short* __restrict__ dst,
                                   int K, int N) {
  __shared__ unsigned short tile[64][70];
  const int bn = blockIdx.x * 64;
  const int bk = blockIdx.y * 64;
  const int tid = threadIdx.x;
  const int rr = tid >> 4, c4 = (tid & 15) * 4;
#pragma unroll
  for (int j = 0; j < 4; ++j) {
    const int r = rr + j * 16;
    float4 v = *(const float4*)(src + (size_t)(bk + r) * N + bn + c4);
    ushort4 u;
    u.x = f2b(v.x); u.y = f2b(v.y); u.z = f2b(v.z); u.w = f2b(v.w);
    *(ushort4*)&tile[r][c4] = u;
  }
  __syncthreads();
#pragma unroll
  for (int j = 0; j < 4; ++j) {
    const int n = rr + j * 16;
    ushort4 u;
    u.x = tile[c4 + 0][n];
    u.y = tile[c4 + 1][n];
    u.z = tile[c4 + 2][n];
    u.w = tile[c4 + 3][n];
    *(ushort4*)(dst + (size_t)(bn + n) * K + bk + c4) = u;
  }
}

// ---------------- RMSNorm fp32 -> bf16 (D=2048, 1 block/row) ----------------
__global__ void rmsnorm_kernel(const float* __restrict__ x,
                               const float* __restrict__ w,
                               unsigned short* __restrict__ out) {
  const int row = blockIdx.x;
  const float* xr = x + (size_t)row * DD;
  const int t = threadIdx.x;
  float4 v0 = ((const float4*)xr)[t];
  float4 v1 = ((const float4*)xr)[t + 256];
  float ss = v0.x * v0.x + v0.y * v0.y + v0.z * v0.z + v0.w * v0.w +
             v1.x * v1.x + v1.y * v1.y + v1.z * v1.z + v1.w * v1.w;
#pragma unroll
  for (int off = 32; off >= 1; off >>= 1) ss += __shfl_xor(ss, off);
  __shared__ float sred[4];
  if ((t & 63) == 0) sred[t >> 6] = ss;
  __syncthreads();
  float tot = sred[0] + sred[1] + sred[2] + sred[3];
  float rs = rsqrtf(tot * (1.0f / DD) + 1e-5f);
  float4 w0 = ((const float4*)w)[t];
  float4 w1v = ((const float4*)w)[t + 256];
  unsigned short* orow = out + (size_t)row * DD;
  ushort4 o0, o1;
  o0.x = f2b(v0.x * rs * w0.x); o0.y = f2b(v0.y * rs * w0.y);
  o0.z = f2b(v0.z * rs * w0.z); o0.w = f2b(v0.w * rs * w0.w);
  o1.x = f2b(v1.x * rs * w1v.x); o1.y = f2b(v1.y * rs * w1v.y);
  o1.z = f2b(v1.z * rs * w1v.z); o1.w = f2b(v1.w * rs * w1v.w);
  ((ushort4*)orow)[t] = o0;
  ((ushort4*)orow)[t + 256] = o1;
}

// ---- fused: x2 = p0 + p1 + x ; h2 = rmsnorm(x2) * w  (1 block/row) ---------
__global__ void reduce_rmsnorm_kernel(const float* __restrict__ p0,
                                      const float* __restrict__ p1,
                                      const float* __restrict__ x,
                                      const float* __restrict__ w,
                                      float* __restrict__ x2,
                                      unsigned short* __restrict__ h2) {
  const int row = blockIdx.x;
  const size_t base = (size_t)row * DD;
  const int t = threadIdx.x;
  float4 a0 = ((const float4*)(p0 + base))[t];
  float4 a1 = ((const float4*)(p0 + base))[t + 256];
  float4 b0 = ((const float4*)(p1 + base))[t];
  float4 b1 = ((const float4*)(p1 + base))[t + 256];
  float4 c0 = ((const float4*)(x + base))[t];
  float4 c1 = ((const float4*)(x + base))[t + 256];
  float4 s0, s1;
  s0.x = a0.x + b0.x + c0.x; s0.y = a0.y + b0.y + c0.y;
  s0.z = a0.z + b0.z + c0.z; s0.w = a0.w + b0.w + c0.w;
  s1.x = a1.x + b1.x + c1.x; s1.y = a1.y + b1.y + c1.y;
  s1.z = a1.z + b1.z + c1.z; s1.w = a1.w + b1.w + c1.w;
  ((float4*)(x2 + base))[t] = s0;
  ((float4*)(x2 + base))[t + 256] = s1;
  float ss = s0.x * s0.x + s0.y * s0.y + s0.z * s0.z + s0.w * s0.w +
             s1.x * s1.x + s1.y * s1.y + s1.z * s1.z + s1.w * s1.w;
#pragma unroll
  for (int off = 32; off >= 1; off >>= 1) ss += __shfl_xor(ss, off);
  __shared__ float sred[4];
  if ((t & 63) == 0) sred[t >> 6] = ss;
  __syncthreads();
  float tot = sred[0] + sred[1] + sred[2] + sred[3];
  float rs = rsqrtf(tot * (1.0f / DD) + 1e-5f);
  float4 w0 = ((const float4*)w)[t];
  float4 w1v = ((const float4*)w)[t + 256];
  ushort4 o0, o1;
  o0.x = f2b(s0.x * rs * w0.x); o0.y = f2b(s0.y * rs * w0.y);
  o0.z = f2b(s0.z * rs * w0.z); o0.w = f2b(s0.w * rs * w0.w);
  o1.x = f2b(s1.x * rs * w1v.x); o1.y = f2b(s1.y * rs * w1v.y);
  o1.z = f2b(s1.z * rs * w1v.z); o1.w = f2b(s1.w * rs * w1v.w);
  unsigned short* orow = h2 + base;
  ((ushort4*)orow)[t] = o0;
  ((ushort4*)orow)[t + 256] = o1;
}

// ---- out = p0 + p1 + x2 (float4 elementwise) -------------------------------
__global__ void add3_kernel(const float4* __restrict__ p0,
                            const float4* __restrict__ p1,
                            const float4* __restrict__ x2,
                            float4* __restrict__ out, int n4) {
  const int i = blockIdx.x * 256 + threadIdx.x;
  if (i >= n4) return;
  float4 a = p0[i], b = p1[i], c = x2[i], r;
  r.x = a.x + b.x + c.x; r.y = a.y + b.y + c.y;
  r.z = a.z + b.z + c.z; r.w = a.w + b.w + c.w;
  out[i] = r;
}

// ---------------- GEMM (m97-style 128x128): C = A * Bt^T --------------------
// EPI 0: C bf16.  EPI 1: C fp32 = acc + resid.
// EPI 2: split-K partial: z = blockIdx.z selects K-slice [z*K,(z+1)*K); store
//        fp32 acc to Cout + z*pstride.
template <int EPI>
__global__ void gemm_bt(const unsigned short* __restrict__ A, int lda,
                        const unsigned short* __restrict__ Bt, int ldb,
                        int K,
                        const float* __restrict__ resid,
                        void* __restrict__ Cout, int ldc, size_t pstride) {
  __shared__ __align__(16) unsigned short As[128 * 32];
  __shared__ __align__(16) unsigned short Bs[128 * 32];
  const int bm = blockIdx.y * 128;
  const int bn = blockIdx.x * 128;
  if (EPI == 2) {
    const size_t kz = (size_t)blockIdx.z * K;
    A += kz;
    Bt += kz;
  }
  float* Pout = (float*)Cout + (EPI == 2 ? (size_t)blockIdx.z * pstride : 0);
  const int tid = threadIdx.x;
  const int lane = tid & 63;
  const int L = lane & 15, G = lane >> 4;
  const int w = tid >> 6;
  const int wr = (w >> 1) * 64, wc = (w & 1) * 64;

  const f32x4 zero = {0.f, 0.f, 0.f, 0.f};
  f32x4 acc[4][4];
#pragma unroll
  for (int m = 0; m < 4; ++m)
#pragma unroll
    for (int n = 0; n < 4; ++n) acc[m][n] = zero;

  const int srow = w * 32 + (lane >> 2);
  const int scol = (lane & 3) * 8;
  const unsigned short* gA = A + (size_t)(bm + srow) * lda + scol;
  const unsigned short* gB = Bt + (size_t)(bn + srow) * ldb + scol;
  unsigned short* lA0 = &As[w * 1024];
  unsigned short* lA1 = &As[w * 1024 + 512];
  unsigned short* lB0 = &Bs[w * 1024];
  unsigned short* lB1 = &Bs[w * 1024 + 512];

  const int nk = K >> 5;
  for (int kt = 0; kt < nk; ++kt) {
    const int ko = kt * 32;
    __syncthreads();
    gload16(gA + ko, lA0);
    gload16(gA + (size_t)16 * lda + ko, lA1);
    gload16(gB + ko, lB0);
    gload16(gB + (size_t)16 * ldb + ko, lB1);
    __syncthreads();
    bf16x8 af[4], bfr[4];
#pragma unroll
    for (int m = 0; m < 4; ++m)
      af[m] = *reinterpret_cast<const bf16x8*>(&As[(wr + m * 16 + L) * 32 + G * 8]);
#pragma unroll
    for (int n = 0; n < 4; ++n)
      bfr[n] = *reinterpret_cast<const bf16x8*>(&Bs[(wc + n * 16 + L) * 32 + G * 8]);
#pragma unroll
    for (int m = 0; m < 4; ++m)
#pragma unroll
      for (int n = 0; n < 4; ++n)
        acc[m][n] = __builtin_amdgcn_mfma_f32_16x16x32_bf16(af[m], bfr[n], acc[m][n], 0, 0, 0);
  }

#pragma unroll
  for (int m = 0; m < 4; ++m)
#pragma unroll
    for (int n = 0; n < 4; ++n)
#pragma unroll
      for (int i = 0; i < 4; ++i) {
        const int r = bm + wr + m * 16 + G * 4 + i;
        const int c = bn + wc + n * 16 + L;
        const float val = acc[m][n][i];
        if constexpr (EPI == 0) {
          ((unsigned short*)Cout)[(size_t)r * ldc + c] = f2b(val);
        } else if constexpr (EPI == 1) {
          ((float*)Cout)[(size_t)r * ldc + c] = val + resid[(size_t)r * ldc + c];
        } else {
          Pout[(size_t)r * ldc + c] = val;
        }
      }
}

// ---------------- Wide pipelined GEMM: 128x256 tile, 8 waves, BK=32 ---------
template <int EPI>
__launch_bounds__(512, 2)
__global__ void gemm_bt_wide(const unsigned short* __restrict__ A, int lda,
                             const unsigned short* __restrict__ Bt, int ldb,
                             int K,
                             const float* __restrict__ resid,
                             void* __restrict__ Cout, int ldc) {
  __shared__ __align__(16) unsigned short As[4][128 * 32];
  __shared__ __align__(16) unsigned short Bs[4][256 * 32];
  const int bm = blockIdx.y * 128;
  const int bn = blockIdx.x * 256;
  const int tid = threadIdx.x;
  const int lane = tid & 63;
  const int L = lane & 15, G = lane >> 4;
  const int w = tid >> 6;
  const int wr = (w >> 2) * 64;
  const int wc = (w & 3) * 64;

  const f32x4 zero = {0.f, 0.f, 0.f, 0.f};
  f32x4 acc[4][4];
#pragma unroll
  for (int m = 0; m < 4; ++m)
#pragma unroll
    for (int n = 0; n < 4; ++n) acc[m][n] = zero;

  const int arow = tid >> 2;
  const int slot = (tid & 3) * 8;
  const unsigned short* gA = A + (size_t)(bm + arow) * lda + slot;
  const unsigned short* gB0 = Bt + (size_t)(bn + arow) * ldb + slot;
  const unsigned short* gB1 = Bt + (size_t)(bn + 128 + arow) * ldb + slot;
  const int ldsA = w * 512;
  const int ldsB0 = w * 512;
  const int ldsB1 = 4096 + w * 512;

  const int nk = K >> 5;

  gload16(gA, &As[0][ldsA]);
  gload16(gB0, &Bs[0][ldsB0]);
  gload16(gB1, &Bs[0][ldsB1]);
  gload16(gA + 32, &As[1][ldsA]);
  gload16(gB0 + 32, &Bs[1][ldsB0]);
  gload16(gB1 + 32, &Bs[1][ldsB1]);

  int cb = 0;
  int ko = 64;

  auto COMPUTE = [&](int b) {
    bf16x8 af[4], bfr[4];
#pragma unroll
    for (int m = 0; m < 4; ++m)
      af[m] = *reinterpret_cast<const bf16x8*>(&As[b][(wr + m * 16 + L) * 32 + G * 8]);
#pragma unroll
    for (int n = 0; n < 4; ++n)
      bfr[n] = *reinterpret_cast<const bf16x8*>(&Bs[b][(wc + n * 16 + L) * 32 + G * 8]);
    __builtin_amdgcn_s_setprio(1);
#pragma unroll
    for (int m = 0; m < 4; ++m)
#pragma unroll
      for (int n = 0; n < 4; ++n)
        acc[m][n] = __builtin_amdgcn_mfma_f32_16x16x32_bf16(af[m], bfr[n], acc[m][n], 0, 0, 0);
    __builtin_amdgcn_s_setprio(0);
  };

  for (int t = 0; t < nk - 2; ++t) {
    const int sb = (cb + 2) & 3;
    gload16(gA + ko, &As[sb][ldsA]);
    gload16(gB0 + ko, &Bs[sb][ldsB0]);
    gload16(gB1 + ko, &Bs[sb][ldsB1]);
    ko += 32;
    WAITVM(6);
    BARRIER();
    COMPUTE(cb);
    cb = (cb + 1) & 3;
  }
  WAITVM(3);
  BARRIER();
  COMPUTE(cb);
  cb = (cb + 1) & 3;
  WAITVM(0);
  BARRIER();
  COMPUTE(cb);

#pragma unroll
  for (int m = 0; m < 4; ++m)
#pragma unroll
    for (int n = 0; n < 4; ++n)
#pragma unroll
      for (int i = 0; i < 4; ++i) {
        const int r = bm + wr + m * 16 + G * 4 + i;
        const int c = bn + wc + n * 16 + L;
        const float val = acc[m][n][i];
        if constexpr (EPI == 0) {
          ((unsigned short*)Cout)[(size_t)r * ldc + c] = f2b(val);
        } else {
          ((float*)Cout)[(size_t)r * ldc + c] = val + resid[(size_t)r * ldc + c];
        }
      }
}

// ---------------- Flash attention, causal GQA -------------------------------
// blockIdx.y is folded so that any contiguous / strided CU assignment gets a
// near-constant total tile count (work(qb) = qb+1; fold pairs small+large).
__launch_bounds__(256, 2)
__global__ void attn_kernel(const unsigned short* __restrict__ qkv,
                            unsigned short* __restrict__ out) {
  const int hq = blockIdx.x;
  const int yy = blockIdx.y;
  const int q8 = yy & 7, seg = yy >> 3;
  const int qb = (seg == 0) ? q8 : (seg == 1) ? 31 - q8 : (seg == 2) ? 8 + q8 : 23 - q8;
  const int hkv = hq >> 2;
  const int tid = threadIdx.x, lane = tid & 63, w = tid >> 6;
  const int L = lane & 15, G = lane >> 4;

  __shared__ __align__(16) unsigned short Ks[64 * 72];
  __shared__ __align__(16) unsigned short Vt[64 * 72];
  __shared__ __align__(16) unsigned short Ps[4][16 * 72];

  const int qrow = qb * 64 + w * 16;
  bf16x8 qf[2];
#pragma unroll
  for (int d0 = 0; d0 < 2; ++d0)
    qf[d0] = *reinterpret_cast<const bf16x8*>(
        qkv + (size_t)(qrow + L) * 3072 + hq * 64 + d0 * 32 + G * 8);

  const f32x4 zero = {0.f, 0.f, 0.f, 0.f};
  f32x4 o[4];
#pragma unroll
  for (int n = 0; n < 4; ++n) o[n] = zero;
  float mrow[4], lrow[4];
#pragma unroll
  for (int i = 0; i < 4; ++i) { mrow[i] = -1e30f; lrow[i] = 0.f; }

  const int ntile = qb + 1;
  for (int t = 0; t < ntile; ++t) {
    const int s0 = t * 64;
    __syncthreads();
#pragma unroll
    for (int i2 = 0; i2 < 2; ++i2) {
      const int c = i2 * 256 + tid;
      const int r = c >> 3, col = (c & 7) * 8;
      bf16x8 k8 = *reinterpret_cast<const bf16x8*>(
          qkv + (size_t)(s0 + r) * 3072 + 2048 + hkv * 64 + col);
      *reinterpret_cast<bf16x8*>(&Ks[r * 72 + col]) = k8;
      short8 v8 = *reinterpret_cast<const short8*>(
          qkv + (size_t)(s0 + r) * 3072 + 2560 + hkv * 64 + col);
#pragma unroll
      for (int j = 0; j < 8; ++j) {
        const int d = col + j;
        Vt[d * 72 + (r ^ (((d >> 3) & 7) << 3))] = (unsigned short)v8[j];
      }
    }
    __syncthreads();

    f32x4 sacc[4];
#pragma unroll
    for (int nt = 0; nt < 4; ++nt) {
      sacc[nt] = zero;
#pragma unroll
      for (int d0 = 0; d0 < 2; ++d0) {
        bf16x8 kf = *reinterpret_cast<const bf16x8*>(
            &Ks[(nt * 16 + L) * 72 + d0 * 32 + G * 8]);
        sacc[nt] = __builtin_amdgcn_mfma_f32_16x16x32_bf16(qf[d0], kf, sacc[nt], 0, 0, 0);
      }
    }

    const bool diag = (t == qb);
    float pt[4][4];
#pragma unroll
    for (int i = 0; i < 4; ++i) {
      const int q = qrow + G * 4 + i;
      float mx = mrow[i];
#pragma unroll
      for (int nt = 0; nt < 4; ++nt) {
        float sv = sacc[nt][i] * 0.125f;
        if (diag) {
          const int s = s0 + nt * 16 + L;
          sv = (s <= q) ? sv : -1e30f;
        }
        pt[i][nt] = sv;
        mx = fmaxf(mx, sv);
      }
#pragma unroll
      for (int off = 1; off < 16; off <<= 1) mx = fmaxf(mx, __shfl_xor(mx, off));
      const float scale_o = __expf(mrow[i] - mx);
      float rsum = 0.f;
#pragma unroll
      for (int nt = 0; nt < 4; ++nt) {
        const float p = __expf(pt[i][nt] - mx);
        pt[i][nt] = p;
        rsum += p;
      }
#pragma unroll
      for (int off = 1; off < 16; off <<= 1) rsum += __shfl_xor(rsum, off);
      mrow[i] = mx;
      lrow[i] = lrow[i] * scale_o + rsum;
#pragma unroll
      for (int nt = 0; nt < 4; ++nt) o[nt][i] *= scale_o;
    }

#pragma unroll
    for (int i = 0; i < 4; ++i) {
      const int prow = G * 4 + i;
#pragma unroll
      for (int nt = 0; nt < 4; ++nt)
        Ps[w][prow * 72 + ((nt * 16 + L) ^ ((prow & 7) << 3))] = f2b(pt[i][nt]);
    }
#pragma unroll
    for (int kc = 0; kc < 2; ++kc) {
      bf16x8 pf = *reinterpret_cast<const bf16x8*>(
          &Ps[w][L * 72 + ((kc * 32 + G * 8) ^ ((L & 7) << 3))]);
#pragma unroll
      for (int nt = 0; nt < 4; ++nt) {
        const int vrow = nt * 16 + L;
        bf16x8 vf = *reinterpret_cast<const bf16x8*>(
            &Vt[vrow * 72 + ((kc * 32 + G * 8) ^ (((vrow >> 3) & 7) << 3))]);
        o[nt] = __builtin_amdgcn_mfma_f32_16x16x32_bf16(pf, vf, o[nt], 0, 0, 0);
      }
    }
  }

#pragma unroll
  for (int nt = 0; nt < 4; ++nt)
#pragma unroll
    for (int i = 0; i < 4; ++i) {
      const float val = o[nt][i] / lrow[i];
      out[(size_t)(qrow + G * 4 + i) * 2048 + hq * 64 + nt * 16 + L] = f2b(val);
    }
}

// ---------------- SwiGLU in-place over gate half of fc1 ---------------------
__global__ void swiglu_kernel(unsigned short* __restrict__ fc1) {
  const size_t total = (size_t)TT * (II / 8);
  const size_t idx = (size_t)blockIdx.x * blockDim.x + threadIdx.x;
  if (idx >= total) return;
  const int m = (int)(idx / (II / 8));
  const int jc = (int)(idx % (II / 8));
  unsigned short* g = fc1 + (size_t)m * (2 * II) + jc * 8;
  short8 gv = *(const short8*)g;
  short8 vv = *(const short8*)(g + II);
  short8 ov;
#pragma unroll
  for (int j = 0; j < 8; ++j) {
    const float gf = b2f((unsigned short)gv[j]);
    const float vf = b2f((unsigned short)vv[j]);
    const float s = gf / (1.f + __expf(-gf));
    ov[j] = (short)f2b(s * vf);
  }
  *(short8*)g = ov;
}

// ---------------- launch ----------------------------------------------------
extern "C" void kernel_launch(void* const* d_in, const int* in_sizes, int n_in,
                              void* d_out, int out_size, void* d_ws, size_t ws_size,
                              hipStream_t stream) {
  const float* x    = (const float*)d_in[0];
  const float* ln1w = (const float*)d_in[1];
  const float* ln2w = (const float*)d_in[2];
  const float* wq   = (const float*)d_in[3];
  const float* wk   = (const float*)d_in[4];
  const float* wv   = (const float*)d_in[5];
  const float* wo   = (const float*)d_in[6];
  const float* w1   = (const float*)d_in[7];
  const float* w2   = (const float*)d_in[8];
  float* outp = (float*)d_out;

  char* ws = (char*)d_ws;
  size_t off = 0;
  auto alloc = [&](size_t bytes) {
    char* p = ws + off;
    off += (bytes + 255) & ~(size_t)255;
    return p;
  };
  unsigned short* wqkvT = (unsigned short*)alloc((size_t)3072 * 2048 * 2);
  unsigned short* woT   = (unsigned short*)alloc((size_t)2048 * 2048 * 2);
  unsigned short* w1T   = (unsigned short*)alloc((size_t)11264 * 2048 * 2);
  unsigned short* w2T   = (unsigned short*)alloc((size_t)2048 * 5632 * 2);
  unsigned short* h     = (unsigned short*)alloc((size_t)2048 * 2048 * 2);
  unsigned short* qkv   = (unsigned short*)alloc((size_t)2048 * 3072 * 2);
  unsigned short* attnb = (unsigned short*)alloc((size_t)2048 * 2048 * 2);
  float*          x2    = (float*)alloc((size_t)2048 * 2048 * 4);
  unsigned short* h2    = (unsigned short*)alloc((size_t)2048 * 2048 * 2);
  unsigned short* fc1   = (unsigned short*)alloc((size_t)2048 * 11264 * 2);
  float*          part  = (float*)alloc((size_t)2 * 2048 * 2048 * 4);  // split-K partials
  const bool use_split = (off <= ws_size);
  (void)in_sizes; (void)n_in; (void)out_size;

  transpose_f32_bf16<<<dim3(2048 / 64, 2048 / 64), 256, 0, stream>>>(wq, wqkvT, 2048, 2048);
  transpose_f32_bf16<<<dim3(512 / 64, 2048 / 64), 256, 0, stream>>>(wk, wqkvT + (size_t)2048 * 2048, 2048, 512);
  transpose_f32_bf16<<<dim3(512 / 64, 2048 / 64), 256, 0, stream>>>(wv, wqkvT + (size_t)2560 * 2048, 2048, 512);
  transpose_f32_bf16<<<dim3(2048 / 64, 2048 / 64), 256, 0, stream>>>(wo, woT, 2048, 2048);
  transpose_f32_bf16<<<dim3(11264 / 64, 2048 / 64), 256, 0, stream>>>(w1, w1T, 2048, 11264);
  transpose_f32_bf16<<<dim3(2048 / 64, 5632 / 64), 256, 0, stream>>>(w2, w2T, 5632, 2048);

  rmsnorm_kernel<<<2048, 256, 0, stream>>>(x, ln1w, h);

  // QKV fused GEMM: (2048 x 3072) = h @ [wq|wk|wv]
  gemm_bt<0><<<dim3(3072 / 128, 2048 / 128), 256, 0, stream>>>(
      h, 2048, wqkvT, 2048, 2048, nullptr, qkv, 3072, 0);

  attn_kernel<<<dim3(NHQ, TT / 64), 256, 0, stream>>>(qkv, attnb);

  const size_t PS = (size_t)2048 * 2048;
  if (use_split) {
    // wo: split-K=2 -> partials, then fused (p0+p1+x) + rmsnorm
    gemm_bt<2><<<dim3(16, 16, 2), 256, 0, stream>>>(
        attnb, 2048, woT, 2048, 1024, nullptr, part, 2048, PS);
    reduce_rmsnorm_kernel<<<2048, 256, 0, stream>>>(part, part + PS, x, ln2w, x2, h2);
  } else {
    gemm_bt<1><<<dim3(16, 16), 256, 0, stream>>>(
        attnb, 2048, woT, 2048, 2048, x, x2, 2048, 0);
    rmsnorm_kernel<<<2048, 256, 0, stream>>>(x2, ln2w, h2);
  }

  // fc1 = h2 @ w1  (2048 x 11264) — wide pipelined kernel
  gemm_bt_wide<0><<<dim3(11264 / 256, 2048 / 128), 512, 0, stream>>>(
      h2, 2048, w1T, 2048, 2048, nullptr, fc1, 11264);

  swiglu_kernel<<<5632, 256, 0, stream>>>(fc1);

  if (use_split) {
    // w2: split-K=2 (K=5632 -> 2816 each) -> partials, then out = p0+p1+x2
    gemm_bt<2><<<dim3(16, 16, 2), 256, 0, stream>>>(
        fc1, 11264, w2T, 5632, 2816, nullptr, part, 2048, PS);
    add3_kernel<<<(2048 * 2048 / 4 + 255) / 256, 256, 0, stream>>>(
        (const float4*)part, (const float4*)(part + PS), (const float4*)x2,
        (float4*)outp, 2048 * 2048 / 4);
  } else {
    gemm_bt<1><<<dim3(16, 16), 256, 0, stream>>>(
        fc1, 11264, w2T, 5632, 5632, x2, outp, 2048, 0);
  }
}

// Round 5
// 606.593 us; speedup vs baseline: 1.1864x; 1.0127x over previous
//
#include <hip/hip_runtime.h>
#include <hip/hip_bf16.h>
#include <cstdint>
#include <cstddef>

// Problem constants
#define TT 2048
#define DD 2048
#define NHQ 32
#define NHKV 8
#define DHD 64
#define II 5632

typedef short short8 __attribute__((ext_vector_type(8)));
typedef __bf16 bf16x8 __attribute__((ext_vector_type(8)));
typedef float f32x4 __attribute__((ext_vector_type(4)));

__device__ __forceinline__ float b2f(unsigned short u) {
  union { float f; unsigned int i; } v; v.i = ((unsigned int)u) << 16; return v.f;
}
__device__ __forceinline__ unsigned short f2b(float f) {
  union { float f; unsigned int i; } v; v.f = f;
  unsigned int r = v.i + 0x7FFFu + ((v.i >> 16) & 1u);
  return (unsigned short)(r >> 16);
}

// global -> LDS direct copy, 16B per lane. l is the wave-uniform (lane-0)
// LDS destination; HW adds lane*16.
__device__ __forceinline__ void gload16(const unsigned short* g, unsigned short* l) {
  __builtin_amdgcn_global_load_lds(
      (const __attribute__((address_space(1))) void*)g,
      (__attribute__((address_space(3))) void*)(unsigned int)(uintptr_t)l,
      16, 0, 0);
}

#define WAITVM(N) asm volatile("s_waitcnt vmcnt(" #N ")" ::: "memory")
#define BARRIER() do { asm volatile("" ::: "memory"); __builtin_amdgcn_s_barrier(); \
                       asm volatile("" ::: "memory"); } while (0)
#define LGKM0() do { asm volatile("s_waitcnt lgkmcnt(0)" ::: "memory"); \
                     __builtin_amdgcn_sched_barrier(0); } while (0)

// ---------------- transpose fp32 (K x N) -> bf16 (N x K), 64x64 tiles -------
__global__ void transpose_f32_bf16(const float* __restrict__ src,
                                   unsigned short* __restrict__ dst,
                                   int K, int N) {
  __shared__ unsigned short tile[64][70];
  const int bn = blockIdx.x * 64;
  const int bk = blockIdx.y * 64;
  const int tid = threadIdx.x;
  const int rr = tid >> 4, c4 = (tid & 15) * 4;
#pragma unroll
  for (int j = 0; j < 4; ++j) {
    const int r = rr + j * 16;
    float4 v = *(const float4*)(src + (size_t)(bk + r) * N + bn + c4);
    ushort4 u;
    u.x = f2b(v.x); u.y = f2b(v.y); u.z = f2b(v.z); u.w = f2b(v.w);
    *(ushort4*)&tile[r][c4] = u;
  }
  __syncthreads();
#pragma unroll
  for (int j = 0; j < 4; ++j) {
    const int n = rr + j * 16;
    ushort4 u;
    u.x = tile[c4 + 0][n];
    u.y = tile[c4 + 1][n];
    u.z = tile[c4 + 2][n];
    u.w = tile[c4 + 3][n];
    *(ushort4*)(dst + (size_t)(bn + n) * K + bk + c4) = u;
  }
}

// ---------------- RMSNorm fp32 -> bf16 (D=2048, 1 block/row) ----------------
__global__ void rmsnorm_kernel(const float* __restrict__ x,
                               const float* __restrict__ w,
                               unsigned short* __restrict__ out) {
  const int row = blockIdx.x;
  const float* xr = x + (size_t)row * DD;
  const int t = threadIdx.x;
  float4 v0 = ((const float4*)xr)[t];
  float4 v1 = ((const float4*)xr)[t + 256];
  float ss = v0.x * v0.x + v0.y * v0.y + v0.z * v0.z + v0.w * v0.w +
             v1.x * v1.x + v1.y * v1.y + v1.z * v1.z + v1.w * v1.w;
#pragma unroll
  for (int off = 32; off >= 1; off >>= 1) ss += __shfl_xor(ss, off);
  __shared__ float sred[4];
  if ((t & 63) == 0) sred[t >> 6] = ss;
  __syncthreads();
  float tot = sred[0] + sred[1] + sred[2] + sred[3];
  float rs = rsqrtf(tot * (1.0f / DD) + 1e-5f);
  float4 w0 = ((const float4*)w)[t];
  float4 w1v = ((const float4*)w)[t + 256];
  unsigned short* orow = out + (size_t)row * DD;
  ushort4 o0, o1;
  o0.x = f2b(v0.x * rs * w0.x); o0.y = f2b(v0.y * rs * w0.y);
  o0.z = f2b(v0.z * rs * w0.z); o0.w = f2b(v0.w * rs * w0.w);
  o1.x = f2b(v1.x * rs * w1v.x); o1.y = f2b(v1.y * rs * w1v.y);
  o1.z = f2b(v1.z * rs * w1v.z); o1.w = f2b(v1.w * rs * w1v.w);
  ((ushort4*)orow)[t] = o0;
  ((ushort4*)orow)[t + 256] = o1;
}

// ---- fused: x2 = sum(partials) + x ; h2 = rmsnorm(x2) * w  (1 block/row) ---
template <int NP>
__global__ void reduce_rmsnorm_kernel(const float* __restrict__ p, size_t ps,
                                      const float* __restrict__ x,
                                      const float* __restrict__ w,
                                      float* __restrict__ x2,
                                      unsigned short* __restrict__ h2) {
  const int row = blockIdx.x;
  const size_t base = (size_t)row * DD;
  const int t = threadIdx.x;
  float4 s0 = ((const float4*)(x + base))[t];
  float4 s1 = ((const float4*)(x + base))[t + 256];
#pragma unroll
  for (int j = 0; j < NP; ++j) {
    float4 a0 = ((const float4*)(p + j * ps + base))[t];
    float4 a1 = ((const float4*)(p + j * ps + base))[t + 256];
    s0.x += a0.x; s0.y += a0.y; s0.z += a0.z; s0.w += a0.w;
    s1.x += a1.x; s1.y += a1.y; s1.z += a1.z; s1.w += a1.w;
  }
  ((float4*)(x2 + base))[t] = s0;
  ((float4*)(x2 + base))[t + 256] = s1;
  float ss = s0.x * s0.x + s0.y * s0.y + s0.z * s0.z + s0.w * s0.w +
             s1.x * s1.x + s1.y * s1.y + s1.z * s1.z + s1.w * s1.w;
#pragma unroll
  for (int off = 32; off >= 1; off >>= 1) ss += __shfl_xor(ss, off);
  __shared__ float sred[4];
  if ((t & 63) == 0) sred[t >> 6] = ss;
  __syncthreads();
  float tot = sred[0] + sred[1] + sred[2] + sred[3];
  float rs = rsqrtf(tot * (1.0f / DD) + 1e-5f);
  float4 w0 = ((const float4*)w)[t];
  float4 w1v = ((const float4*)w)[t + 256];
  ushort4 o0, o1;
  o0.x = f2b(s0.x * rs * w0.x); o0.y = f2b(s0.y * rs * w0.y);
  o0.z = f2b(s0.z * rs * w0.z); o0.w = f2b(s0.w * rs * w0.w);
  o1.x = f2b(s1.x * rs * w1v.x); o1.y = f2b(s1.y * rs * w1v.y);
  o1.z = f2b(s1.z * rs * w1v.z); o1.w = f2b(s1.w * rs * w1v.w);
  unsigned short* orow = h2 + base;
  ((ushort4*)orow)[t] = o0;
  ((ushort4*)orow)[t + 256] = o1;
}

// ---- out = sum(partials) + x2 (float4 elementwise) -------------------------
template <int NP>
__global__ void addres_kernel(const float* __restrict__ p, size_t ps,
                              const float4* __restrict__ x2,
                              float4* __restrict__ out, int n4) {
  const int i = blockIdx.x * 256 + threadIdx.x;
  if (i >= n4) return;
  float4 r = x2[i];
#pragma unroll
  for (int j = 0; j < NP; ++j) {
    float4 a = ((const float4*)(p + j * ps))[i];
    r.x += a.x; r.y += a.y; r.z += a.z; r.w += a.w;
  }
  out[i] = r;
}

// ---------------- GEMM (m97-style 128x128): C = A * Bt^T --------------------
// EPI 0: C bf16.  EPI 1: C fp32 = acc + resid.
template <int EPI>
__global__ void gemm_bt(const unsigned short* __restrict__ A, int lda,
                        const unsigned short* __restrict__ Bt, int ldb,
                        int K,
                        const float* __restrict__ resid,
                        void* __restrict__ Cout, int ldc) {
  __shared__ __align__(16) unsigned short As[128 * 32];
  __shared__ __align__(16) unsigned short Bs[128 * 32];
  const int bm = blockIdx.y * 128;
  const int bn = blockIdx.x * 128;
  const int tid = threadIdx.x;
  const int lane = tid & 63;
  const int L = lane & 15, G = lane >> 4;
  const int w = tid >> 6;
  const int wr = (w >> 1) * 64, wc = (w & 1) * 64;

  const f32x4 zero = {0.f, 0.f, 0.f, 0.f};
  f32x4 acc[4][4];
#pragma unroll
  for (int m = 0; m < 4; ++m)
#pragma unroll
    for (int n = 0; n < 4; ++n) acc[m][n] = zero;

  const int srow = w * 32 + (lane >> 2);
  const int scol = (lane & 3) * 8;
  const unsigned short* gA = A + (size_t)(bm + srow) * lda + scol;
  const unsigned short* gB = Bt + (size_t)(bn + srow) * ldb + scol;
  unsigned short* lA0 = &As[w * 1024];
  unsigned short* lA1 = &As[w * 1024 + 512];
  unsigned short* lB0 = &Bs[w * 1024];
  unsigned short* lB1 = &Bs[w * 1024 + 512];

  const int nk = K >> 5;
  for (int kt = 0; kt < nk; ++kt) {
    const int ko = kt * 32;
    __syncthreads();
    gload16(gA + ko, lA0);
    gload16(gA + (size_t)16 * lda + ko, lA1);
    gload16(gB + ko, lB0);
    gload16(gB + (size_t)16 * ldb + ko, lB1);
    __syncthreads();
    bf16x8 af[4], bfr[4];
#pragma unroll
    for (int m = 0; m < 4; ++m)
      af[m] = *reinterpret_cast<const bf16x8*>(&As[(wr + m * 16 + L) * 32 + G * 8]);
#pragma unroll
    for (int n = 0; n < 4; ++n)
      bfr[n] = *reinterpret_cast<const bf16x8*>(&Bs[(wc + n * 16 + L) * 32 + G * 8]);
#pragma unroll
    for (int m = 0; m < 4; ++m)
#pragma unroll
      for (int n = 0; n < 4; ++n)
        acc[m][n] = __builtin_amdgcn_mfma_f32_16x16x32_bf16(af[m], bfr[n], acc[m][n], 0, 0, 0);
  }

#pragma unroll
  for (int m = 0; m < 4; ++m)
#pragma unroll
    for (int n = 0; n < 4; ++n)
#pragma unroll
      for (int i = 0; i < 4; ++i) {
        const int r = bm + wr + m * 16 + G * 4 + i;
        const int c = bn + wc + n * 16 + L;
        const float val = acc[m][n][i];
        if constexpr (EPI == 0) {
          ((unsigned short*)Cout)[(size_t)r * ldc + c] = f2b(val);
        } else {
          ((float*)Cout)[(size_t)r * ldc + c] = val + resid[(size_t)r * ldc + c];
        }
      }
}

// ---------------- 256x256 phase-pipelined GEMM engine -----------------------
// 8 waves (2M x 4N), per-wave 128x64 output (acc[8][4]), BK=32.
// 4 LDS buffers (128 KB), depth-2 prefetch, counted vmcnt, 2 phases/K-step:
//   top:  WAITVM(4) [tile t resident for this wave] ; BARRIER [all waves]
//   ph1:  stage A-half of tile t+2 | ds_read af[0..3]+bfr[0..3] | lgkm0 |
//         setprio(1) 16 MFMA (m=0..3) setprio(0) ; BARRIER
//   ph2:  stage B-half of tile t+2 | ds_read af[4..7]           | lgkm0 |
//         setprio(1) 16 MFMA (m=4..7) setprio(0)
// Race ledger: stage target buf[(t+2)&3]; readers buf[t&3]; distance 2 mod 4.
// buf[(t+2)&3]'s previous readers (step t-2) drained their ds_reads (lgkm0)
// before the top barrier of step t-1 < issue point. vmcnt per wave: 4 loads
// issued per step; WAITVM(4) at top of step t ensures tile t's loads retired.
// EPI 0: C bf16.  EPI 2: fp32 partial at Cout + blockIdx.z*pstride (split-K).
template <int EPI>
__launch_bounds__(512, 2)
__global__ void gemm256(const unsigned short* __restrict__ A, int lda,
                        const unsigned short* __restrict__ Bt, int ldb,
                        int K,
                        void* __restrict__ Cout, int ldc, size_t pstride) {
  __shared__ __align__(16) unsigned short As[4][256 * 32];
  __shared__ __align__(16) unsigned short Bs[4][256 * 32];
  const int bm = blockIdx.y * 256;
  const int bn = blockIdx.x * 256;
  if constexpr (EPI == 2) {
    const size_t kz = (size_t)blockIdx.z * K;
    A += kz;
    Bt += kz;
  }
  const int tid = threadIdx.x;
  const int lane = tid & 63;
  const int L = lane & 15, G = lane >> 4;
  const int w = tid >> 6;            // 0..7
  const int wr = (w >> 2) * 128;     // 0 / 128
  const int wc = (w & 3) * 64;       // 0/64/128/192

  const f32x4 zero = {0.f, 0.f, 0.f, 0.f};
  f32x4 acc[8][4];
#pragma unroll
  for (int m = 0; m < 8; ++m)
#pragma unroll
    for (int n = 0; n < 4; ++n) acc[m][n] = zero;

  // staging addresses: each line = 512 threads x 16B = 8KB = 128 rows x 32 k
  const int srow = tid >> 2;          // 0..127
  const int scol = (tid & 3) * 8;     // 0/8/16/24
  const unsigned short* gA0 = A + (size_t)(bm + srow) * lda + scol;
  const unsigned short* gA1 = A + (size_t)(bm + 128 + srow) * lda + scol;
  const unsigned short* gB0 = Bt + (size_t)(bn + srow) * ldb + scol;
  const unsigned short* gB1 = Bt + (size_t)(bn + 128 + srow) * ldb + scol;
  const int seg = w * 512;            // per-wave LDS segment (shorts)

  const int nk = K >> 5;              // requires nk >= 2

  // prologue: stage tiles 0 and 1 (4 loads each per wave)
  gload16(gA0, &As[0][seg]);
  gload16(gA1, &As[0][4096 + seg]);
  gload16(gB0, &Bs[0][seg]);
  gload16(gB1, &Bs[0][4096 + seg]);
  gload16(gA0 + 32, &As[1][seg]);
  gload16(gA1 + 32, &As[1][4096 + seg]);
  gload16(gB0 + 32, &Bs[1][seg]);
  gload16(gB1 + 32, &Bs[1][4096 + seg]);

  bf16x8 af1[4], af2[4], bfr[4];

  auto PH1 = [&](int b) {
#pragma unroll
    for (int m = 0; m < 4; ++m)
      af1[m] = *reinterpret_cast<const bf16x8*>(&As[b][(wr + m * 16 + L) * 32 + G * 8]);
#pragma unroll
    for (int n = 0; n < 4; ++n)
      bfr[n] = *reinterpret_cast<const bf16x8*>(&Bs[b][(wc + n * 16 + L) * 32 + G * 8]);
    LGKM0();
    __builtin_amdgcn_s_setprio(1);
#pragma unroll
    for (int m = 0; m < 4; ++m)
#pragma unroll
      for (int n = 0; n < 4; ++n)
        acc[m][n] = __builtin_amdgcn_mfma_f32_16x16x32_bf16(af1[m], bfr[n], acc[m][n], 0, 0, 0);
    __builtin_amdgcn_s_setprio(0);
    __builtin_amdgcn_sched_barrier(0);
  };
  auto PH2 = [&](int b) {
#pragma unroll
    for (int m = 0; m < 4; ++m)
      af2[m] = *reinterpret_cast<const bf16x8*>(&As[b][(wr + 64 + m * 16 + L) * 32 + G * 8]);
    LGKM0();
    __builtin_amdgcn_s_setprio(1);
#pragma unroll
    for (int m = 0; m < 4; ++m)
#pragma unroll
      for (int n = 0; n < 4; ++n)
        acc[4 + m][n] = __builtin_amdgcn_mfma_f32_16x16x32_bf16(af2[m], bfr[n], acc[4 + m][n], 0, 0, 0);
    __builtin_amdgcn_s_setprio(0);
    __builtin_amdgcn_sched_barrier(0);
  };

  int t = 0;
  for (; t < nk - 2; ++t) {
    const int b = t & 3;
    const int sb = (t + 2) & 3;
    const int ko2 = (t + 2) * 32;
    WAITVM(4);
    BARRIER();
    gload16(gA0 + ko2, &As[sb][seg]);
    gload16(gA1 + ko2, &As[sb][4096 + seg]);
    PH1(b);
    BARRIER();
    gload16(gB0 + ko2, &Bs[sb][seg]);
    gload16(gB1 + ko2, &Bs[sb][4096 + seg]);
    PH2(b);
  }
  // t = nk-2 (no staging)
  WAITVM(4);
  BARRIER();
  PH1((nk - 2) & 3);
  BARRIER();
  PH2((nk - 2) & 3);
  // t = nk-1
  WAITVM(0);
  BARRIER();
  PH1((nk - 1) & 3);
  BARRIER();
  PH2((nk - 1) & 3);

#pragma unroll
  for (int m = 0; m < 8; ++m)
#pragma unroll
    for (int n = 0; n < 4; ++n)
#pragma unroll
      for (int i = 0; i < 4; ++i) {
        const int r = bm + wr + m * 16 + G * 4 + i;
        const int c = bn + wc + n * 16 + L;
        const float val = acc[m][n][i];
        if constexpr (EPI == 0) {
          ((unsigned short*)Cout)[(size_t)r * ldc + c] = f2b(val);
        } else {
          ((float*)Cout + (size_t)blockIdx.z * pstride)[(size_t)r * ldc + c] = val;
        }
      }
}

// ---------------- Flash attention, causal GQA -------------------------------
__launch_bounds__(256, 2)
__global__ void attn_kernel(const unsigned short* __restrict__ qkv,
                            unsigned short* __restrict__ out) {
  const int hq = blockIdx.x;
  const int yy = blockIdx.y;
  const int q8 = yy & 7, seg = yy >> 3;
  const int qb = (seg == 0) ? q8 : (seg == 1) ? 31 - q8 : (seg == 2) ? 8 + q8 : 23 - q8;
  const int hkv = hq >> 2;
  const int tid = threadIdx.x, lane = tid & 63, w = tid >> 6;
  const int L = lane & 15, G = lane >> 4;

  __shared__ __align__(16) unsigned short Ks[64 * 72];
  __shared__ __align__(16) unsigned short Vt[64 * 72];
  __shared__ __align__(16) unsigned short Ps[4][16 * 72];

  const int qrow = qb * 64 + w * 16;
  bf16x8 qf[2];
#pragma unroll
  for (int d0 = 0; d0 < 2; ++d0)
    qf[d0] = *reinterpret_cast<const bf16x8*>(
        qkv + (size_t)(qrow + L) * 3072 + hq * 64 + d0 * 32 + G * 8);

  const f32x4 zero = {0.f, 0.f, 0.f, 0.f};
  f32x4 o[4];
#pragma unroll
  for (int n = 0; n < 4; ++n) o[n] = zero;
  float mrow[4], lrow[4];
#pragma unroll
  for (int i = 0; i < 4; ++i) { mrow[i] = -1e30f; lrow[i] = 0.f; }

  const int ntile = qb + 1;
  for (int t = 0; t < ntile; ++t) {
    const int s0 = t * 64;
    __syncthreads();
#pragma unroll
    for (int i2 = 0; i2 < 2; ++i2) {
      const int c = i2 * 256 + tid;
      const int r = c >> 3, col = (c & 7) * 8;
      bf16x8 k8 = *reinterpret_cast<const bf16x8*>(
          qkv + (size_t)(s0 + r) * 3072 + 2048 + hkv * 64 + col);
      *reinterpret_cast<bf16x8*>(&Ks[r * 72 + col]) = k8;
      short8 v8 = *reinterpret_cast<const short8*>(
          qkv + (size_t)(s0 + r) * 3072 + 2560 + hkv * 64 + col);
#pragma unroll
      for (int j = 0; j < 8; ++j) {
        const int d = col + j;
        Vt[d * 72 + (r ^ (((d >> 3) & 7) << 3))] = (unsigned short)v8[j];
      }
    }
    __syncthreads();

    f32x4 sacc[4];
#pragma unroll
    for (int nt = 0; nt < 4; ++nt) {
      sacc[nt] = zero;
#pragma unroll
      for (int d0 = 0; d0 < 2; ++d0) {
        bf16x8 kf = *reinterpret_cast<const bf16x8*>(
            &Ks[(nt * 16 + L) * 72 + d0 * 32 + G * 8]);
        sacc[nt] = __builtin_amdgcn_mfma_f32_16x16x32_bf16(qf[d0], kf, sacc[nt], 0, 0, 0);
      }
    }

    const bool diag = (t == qb);
    float pt[4][4];
#pragma unroll
    for (int i = 0; i < 4; ++i) {
      const int q = qrow + G * 4 + i;
      float mx = mrow[i];
#pragma unroll
      for (int nt = 0; nt < 4; ++nt) {
        float sv = sacc[nt][i] * 0.125f;
        if (diag) {
          const int s = s0 + nt * 16 + L;
          sv = (s <= q) ? sv : -1e30f;
        }
        pt[i][nt] = sv;
        mx = fmaxf(mx, sv);
      }
#pragma unroll
      for (int off = 1; off < 16; off <<= 1) mx = fmaxf(mx, __shfl_xor(mx, off));
      const float scale_o = __expf(mrow[i] - mx);
      float rsum = 0.f;
#pragma unroll
      for (int nt = 0; nt < 4; ++nt) {
        const float p = __expf(pt[i][nt] - mx);
        pt[i][nt] = p;
        rsum += p;
      }
#pragma unroll
      for (int off = 1; off < 16; off <<= 1) rsum += __shfl_xor(rsum, off);
      mrow[i] = mx;
      lrow[i] = lrow[i] * scale_o + rsum;
#pragma unroll
      for (int nt = 0; nt < 4; ++nt) o[nt][i] *= scale_o;
    }

#pragma unroll
    for (int i = 0; i < 4; ++i) {
      const int prow = G * 4 + i;
#pragma unroll
      for (int nt = 0; nt < 4; ++nt)
        Ps[w][prow * 72 + ((nt * 16 + L) ^ ((prow & 7) << 3))] = f2b(pt[i][nt]);
    }
#pragma unroll
    for (int kc = 0; kc < 2; ++kc) {
      bf16x8 pf = *reinterpret_cast<const bf16x8*>(
          &Ps[w][L * 72 + ((kc * 32 + G * 8) ^ ((L & 7) << 3))]);
#pragma unroll
      for (int nt = 0; nt < 4; ++nt) {
        const int vrow = nt * 16 + L;
        bf16x8 vf = *reinterpret_cast<const bf16x8*>(
            &Vt[vrow * 72 + ((kc * 32 + G * 8) ^ (((vrow >> 3) & 7) << 3))]);
        o[nt] = __builtin_amdgcn_mfma_f32_16x16x32_bf16(pf, vf, o[nt], 0, 0, 0);
      }
    }
  }

#pragma unroll
  for (int nt = 0; nt < 4; ++nt)
#pragma unroll
    for (int i = 0; i < 4; ++i) {
      const float val = o[nt][i] / lrow[i];
      out[(size_t)(qrow + G * 4 + i) * 2048 + hq * 64 + nt * 16 + L] = f2b(val);
    }
}

// ---------------- SwiGLU in-place over gate half of fc1 ---------------------
__global__ void swiglu_kernel(unsigned short* __restrict__ fc1) {
  const size_t total = (size_t)TT * (II / 8);
  const size_t idx = (size_t)blockIdx.x * blockDim.x + threadIdx.x;
  if (idx >= total) return;
  const int m = (int)(idx / (II / 8));
  const int jc = (int)(idx % (II / 8));
  unsigned short* g = fc1 + (size_t)m * (2 * II) + jc * 8;
  short8 gv = *(const short8*)g;
  short8 vv = *(const short8*)(g + II);
  short8 ov;
#pragma unroll
  for (int j = 0; j < 8; ++j) {
    const float gf = b2f((unsigned short)gv[j]);
    const float vf = b2f((unsigned short)vv[j]);
    const float s = gf / (1.f + __expf(-gf));
    ov[j] = (short)f2b(s * vf);
  }
  *(short8*)g = ov;
}

// ---------------- launch ----------------------------------------------------
extern "C" void kernel_launch(void* const* d_in, const int* in_sizes, int n_in,
                              void* d_out, int out_size, void* d_ws, size_t ws_size,
                              hipStream_t stream) {
  const float* x    = (const float*)d_in[0];
  const float* ln1w = (const float*)d_in[1];
  const float* ln2w = (const float*)d_in[2];
  const float* wq   = (const float*)d_in[3];
  const float* wk   = (const float*)d_in[4];
  const float* wv   = (const float*)d_in[5];
  const float* wo   = (const float*)d_in[6];
  const float* w1   = (const float*)d_in[7];
  const float* w2   = (const float*)d_in[8];
  float* outp = (float*)d_out;

  char* ws = (char*)d_ws;
  size_t off = 0;
  auto alloc = [&](size_t bytes) {
    char* p = ws + off;
    off += (bytes + 255) & ~(size_t)255;
    return p;
  };
  unsigned short* wqkvT = (unsigned short*)alloc((size_t)3072 * 2048 * 2);
  unsigned short* woT   = (unsigned short*)alloc((size_t)2048 * 2048 * 2);
  unsigned short* w1T   = (unsigned short*)alloc((size_t)11264 * 2048 * 2);
  unsigned short* w2T   = (unsigned short*)alloc((size_t)2048 * 5632 * 2);
  unsigned short* h     = (unsigned short*)alloc((size_t)2048 * 2048 * 2);
  unsigned short* qkv   = (unsigned short*)alloc((size_t)2048 * 3072 * 2);
  unsigned short* attnb = (unsigned short*)alloc((size_t)2048 * 2048 * 2);
  float*          x2    = (float*)alloc((size_t)2048 * 2048 * 4);
  unsigned short* h2    = (unsigned short*)alloc((size_t)2048 * 2048 * 2);
  unsigned short* fc1   = (unsigned short*)alloc((size_t)2048 * 11264 * 2);
  const size_t PS = (size_t)2048 * 2048;
  float* part = (float*)(ws + off);
  const int sk = (off + 4 * PS * 4 <= ws_size) ? 4
               : (off + 2 * PS * 4 <= ws_size) ? 2 : 0;
  (void)in_sizes; (void)n_in; (void)out_size;

  transpose_f32_bf16<<<dim3(2048 / 64, 2048 / 64), 256, 0, stream>>>(wq, wqkvT, 2048, 2048);
  transpose_f32_bf16<<<dim3(512 / 64, 2048 / 64), 256, 0, stream>>>(wk, wqkvT + (size_t)2048 * 2048, 2048, 512);
  transpose_f32_bf16<<<dim3(512 / 64, 2048 / 64), 256, 0, stream>>>(wv, wqkvT + (size_t)2560 * 2048, 2048, 512);
  transpose_f32_bf16<<<dim3(2048 / 64, 2048 / 64), 256, 0, stream>>>(wo, woT, 2048, 2048);
  transpose_f32_bf16<<<dim3(11264 / 64, 2048 / 64), 256, 0, stream>>>(w1, w1T, 2048, 11264);
  transpose_f32_bf16<<<dim3(2048 / 64, 5632 / 64), 256, 0, stream>>>(w2, w2T, 5632, 2048);

  rmsnorm_kernel<<<2048, 256, 0, stream>>>(x, ln1w, h);

  // QKV fused GEMM: (2048 x 3072) = h @ [wq|wk|wv]
  gemm_bt<0><<<dim3(3072 / 128, 2048 / 128), 256, 0, stream>>>(
      h, 2048, wqkvT, 2048, 2048, nullptr, qkv, 3072);

  attn_kernel<<<dim3(NHQ, TT / 64), 256, 0, stream>>>(qkv, attnb);

  // wo: x2 = x + attn @ wo ; h2 = rmsnorm(x2)
  if (sk == 4) {
    gemm256<2><<<dim3(8, 8, 4), 512, 0, stream>>>(
        attnb, 2048, woT, 2048, 512, part, 2048, PS);
    reduce_rmsnorm_kernel<4><<<2048, 256, 0, stream>>>(part, PS, x, ln2w, x2, h2);
  } else if (sk == 2) {
    gemm256<2><<<dim3(8, 8, 2), 512, 0, stream>>>(
        attnb, 2048, woT, 2048, 1024, part, 2048, PS);
    reduce_rmsnorm_kernel<2><<<2048, 256, 0, stream>>>(part, PS, x, ln2w, x2, h2);
  } else {
    gemm_bt<1><<<dim3(16, 16), 256, 0, stream>>>(
        attnb, 2048, woT, 2048, 2048, x, x2, 2048);
    rmsnorm_kernel<<<2048, 256, 0, stream>>>(x2, ln2w, h2);
  }

  // fc1 = h2 @ w1  (2048 x 11264) — 256x256 phase-pipelined engine
  gemm256<0><<<dim3(11264 / 256, 2048 / 256), 512, 0, stream>>>(
      h2, 2048, w1T, 2048, 2048, fc1, 11264, 0);

  swiglu_kernel<<<5632, 256, 0, stream>>>(fc1);

  // w2: out = x2 + sw @ w2
  if (sk == 4) {
    gemm256<2><<<dim3(8, 8, 4), 512, 0, stream>>>(
        fc1, 11264, w2T, 5632, 1408, part, 2048, PS);
    addres_kernel<4><<<(2048 * 2048 / 4 + 255) / 256, 256, 0, stream>>>(
        part, PS, (const float4*)x2, (float4*)outp, 2048 * 2048 / 4);
  } else if (sk == 2) {
    gemm256<2><<<dim3(8, 8, 2), 512, 0, stream>>>(
        fc1, 11264, w2T, 5632, 2816, part, 2048, PS);
    addres_kernel<2><<<(2048 * 2048 / 4 + 255) / 256, 256, 0, stream>>>(
        part, PS, (const float4*)x2, (float4*)outp, 2048 * 2048 / 4);
  } else {
    gemm_bt<1><<<dim3(16, 16), 256, 0, stream>>>(
        fc1, 11264, w2T, 5632, 5632, x2, outp, 2048);
  }
}